// Round 1
// baseline (871.083 us; speedup 1.0000x reference)
//
#include <hip/hip_runtime.h>
#include <cmath>

#define BM 64
#define BN 64
#define BK 16
#define SM_CH 32   // L split chunks for softmax

// ---------------------------------------------------------------------------
// GEMM NT: C[m,n] = epi( sum_k A[m,k]*B[n,k] ), A [M,K] rm, B [N,K] rm.
// Batched over blockIdx.z via element strides. Optional bias+tanh epilogue.
// ---------------------------------------------------------------------------
__global__ __launch_bounds__(256) void gemm_nt_kernel(
    const float* __restrict__ Ab, const float* __restrict__ Bb,
    float* __restrict__ Cb, int M, int N, int K,
    long long strideA, long long strideB, long long strideC,
    const float* __restrict__ bias, int do_tanh)
{
    const float* A = Ab + (long long)blockIdx.z * strideA;
    const float* B = Bb + (long long)blockIdx.z * strideB;
    float*       C = Cb + (long long)blockIdx.z * strideC;

    __shared__ float As[BK][BM];
    __shared__ float Bs[BK][BN];

    const int bm = blockIdx.x * BM;
    const int bn = blockIdx.y * BN;
    const int t  = threadIdx.x;
    const int tx = t & 15;        // n micro-tile
    const int ty = t >> 4;        // m micro-tile
    const int lrow = t >> 2;      // 0..63 loader row
    const int lk   = (t & 3) * 4; // 0,4,8,12 loader k

    float acc[4][4] = {};

    for (int k0 = 0; k0 < K; k0 += BK) {
        // A tile (bounds-checked on M; K always %16==0 so float4 ok)
        int arow = bm + lrow;
        float4 av = make_float4(0.f, 0.f, 0.f, 0.f);
        if (arow < M) av = *(const float4*)(A + (long long)arow * K + k0 + lk);
        As[lk+0][lrow] = av.x; As[lk+1][lrow] = av.y;
        As[lk+2][lrow] = av.z; As[lk+3][lrow] = av.w;

        // B tile (N is always a multiple of 64 here)
        int brow = bn + lrow;
        float4 bv = *(const float4*)(B + (long long)brow * K + k0 + lk);
        Bs[lk+0][lrow] = bv.x; Bs[lk+1][lrow] = bv.y;
        Bs[lk+2][lrow] = bv.z; Bs[lk+3][lrow] = bv.w;

        __syncthreads();
        #pragma unroll
        for (int k = 0; k < BK; ++k) {
            float4 a4 = *(const float4*)&As[k][ty * 4];
            float4 b4 = *(const float4*)&Bs[k][tx * 4];
            float ar[4] = {a4.x, a4.y, a4.z, a4.w};
            float br[4] = {b4.x, b4.y, b4.z, b4.w};
            #pragma unroll
            for (int i = 0; i < 4; ++i)
                #pragma unroll
                for (int j = 0; j < 4; ++j)
                    acc[i][j] += ar[i] * br[j];
        }
        __syncthreads();
    }

    #pragma unroll
    for (int i = 0; i < 4; ++i) {
        int row = bm + ty * 4 + i;
        if (row >= M) continue;
        int col = bn + tx * 4;
        float4 v;
        v.x = acc[i][0]; v.y = acc[i][1]; v.z = acc[i][2]; v.w = acc[i][3];
        if (bias) {
            v.x += bias[col+0]; v.y += bias[col+1];
            v.z += bias[col+2]; v.w += bias[col+3];
        }
        if (do_tanh) {
            v.x = tanhf(v.x); v.y = tanhf(v.y);
            v.z = tanhf(v.z); v.w = tanhf(v.w);
        }
        *(float4*)(C + (long long)row * N + col) = v;
    }
}

// ---------------------------------------------------------------------------
// GEMM NN: C[m,n] = sum_k A[m,k]*B[k,n], A [M,K] rm, B [K,N] rm. Batched.
// ---------------------------------------------------------------------------
__global__ __launch_bounds__(256) void gemm_nn_kernel(
    const float* __restrict__ Ab, const float* __restrict__ Bb,
    float* __restrict__ Cb, int M, int N, int K,
    long long strideA, long long strideB, long long strideC)
{
    const float* A = Ab + (long long)blockIdx.z * strideA;
    const float* B = Bb + (long long)blockIdx.z * strideB;
    float*       C = Cb + (long long)blockIdx.z * strideC;

    __shared__ float As[BK][BM];
    __shared__ float Bs[BK][BN];

    const int bm = blockIdx.x * BM;
    const int bn = blockIdx.y * BN;
    const int t  = threadIdx.x;
    const int tx = t & 15;
    const int ty = t >> 4;
    const int lrow = t >> 2;       // A loader
    const int lk   = (t & 3) * 4;
    const int bkrow = t >> 4;      // B loader: 0..15
    const int bncol = (t & 15) * 4;

    float acc[4][4] = {};

    for (int k0 = 0; k0 < K; k0 += BK) {
        int arow = bm + lrow;
        float4 av = make_float4(0.f, 0.f, 0.f, 0.f);
        if (arow < M) av = *(const float4*)(A + (long long)arow * K + k0 + lk);
        As[lk+0][lrow] = av.x; As[lk+1][lrow] = av.y;
        As[lk+2][lrow] = av.z; As[lk+3][lrow] = av.w;

        float4 bv = *(const float4*)(B + (long long)(k0 + bkrow) * N + bn + bncol);
        *(float4*)&Bs[bkrow][bncol] = bv;

        __syncthreads();
        #pragma unroll
        for (int k = 0; k < BK; ++k) {
            float4 a4 = *(const float4*)&As[k][ty * 4];
            float4 b4 = *(const float4*)&Bs[k][tx * 4];
            float ar[4] = {a4.x, a4.y, a4.z, a4.w};
            float br[4] = {b4.x, b4.y, b4.z, b4.w};
            #pragma unroll
            for (int i = 0; i < 4; ++i)
                #pragma unroll
                for (int j = 0; j < 4; ++j)
                    acc[i][j] += ar[i] * br[j];
        }
        __syncthreads();
    }

    #pragma unroll
    for (int i = 0; i < 4; ++i) {
        int row = bm + ty * 4 + i;
        if (row >= M) continue;
        float4 v;
        v.x = acc[i][0]; v.y = acc[i][1]; v.z = acc[i][2]; v.w = acc[i][3];
        *(float4*)(C + (long long)row * N + bn + tx * 4) = v;
    }
}

// ---------------------------------------------------------------------------
// Softmax over the L dim of scores [B, L, S], per (b, s) column.
// Stage 1: per-chunk online (max, sum). Stage 2: merge. Stage 3: write.
// ---------------------------------------------------------------------------
__global__ __launch_bounds__(256) void softmax_part_kernel(
    const float* __restrict__ scores, float* __restrict__ pm,
    float* __restrict__ ps, int L, int S, int chlen)
{
    int s = blockIdx.x * 256 + threadIdx.x;
    int c = blockIdx.y;
    int b = blockIdx.z;
    int l0 = c * chlen;
    int l1 = min(L, l0 + chlen);
    const float* p = scores + (long long)b * L * S + s;
    float m = -INFINITY, sum = 0.f;
    for (int l = l0; l < l1; ++l) {
        float x = p[(long long)l * S];
        float nm = fmaxf(m, x);
        sum = sum * __expf(m - nm) + __expf(x - nm);
        m = nm;
    }
    int idx = (b * SM_CH + c) * S + s;
    pm[idx] = m;
    ps[idx] = sum;
}

__global__ __launch_bounds__(256) void softmax_merge_kernel(
    const float* __restrict__ pm, const float* __restrict__ ps,
    float* __restrict__ fm, float* __restrict__ fsinv, int S)
{
    int s = blockIdx.x * 256 + threadIdx.x;
    int b = blockIdx.y;
    float m = -INFINITY;
    #pragma unroll
    for (int c = 0; c < SM_CH; ++c)
        m = fmaxf(m, pm[(b * SM_CH + c) * S + s]);
    float sum = 0.f;
    #pragma unroll
    for (int c = 0; c < SM_CH; ++c)
        sum += ps[(b * SM_CH + c) * S + s] * __expf(pm[(b * SM_CH + c) * S + s] - m);
    fm[b * S + s] = m;
    fsinv[b * S + s] = 1.f / sum;
}

__global__ __launch_bounds__(256) void softmax_write_kernel(
    float* __restrict__ scores, const float* __restrict__ fm,
    const float* __restrict__ fsinv, int L, int S, int chlen)
{
    int s = blockIdx.x * 256 + threadIdx.x;
    int c = blockIdx.y;
    int b = blockIdx.z;
    float m   = fm[b * S + s];
    float inv = fsinv[b * S + s];
    float* p = scores + (long long)b * L * S + s;
    int l0 = c * chlen;
    int l1 = min(L, l0 + chlen);
    for (int l = l0; l < l1; ++l) {
        float x = p[(long long)l * S];
        p[(long long)l * S] = __expf(x - m) * inv;
    }
}

extern "C" void kernel_launch(void* const* d_in, const int* in_sizes, int n_in,
                              void* d_out, int out_size, void* d_ws, size_t ws_size,
                              hipStream_t stream)
{
    const int Bn = 8, S = 512, D = 768, E = 768, L = 4000;
    const float* lhs   = (const float*)d_in[0];   // [B,S,D]
    const float* label = (const float*)d_in[1];   // [L,E]
    const float* W     = (const float*)d_in[2];   // [E,D]
    const float* bias  = (const float*)d_in[3];   // [E]

    float* weights = (float*)d_out;                          // [B,L,S]
    float* attn    = (float*)d_out + (long long)Bn * L * S;  // [B,L,D]

    float* proj  = (float*)d_ws;                       // [B,S,E]  12.6 MB
    float* pm    = proj + (long long)Bn * S * E;       // [B,SM_CH,S]
    float* ps    = pm   + (long long)Bn * SM_CH * S;
    float* fm    = ps   + (long long)Bn * SM_CH * S;
    float* fsinv = fm   + (long long)Bn * S;

    const int chlen = (L + SM_CH - 1) / SM_CH;  // 125

    // 1) proj = tanh(lhs @ W^T + bias): M=B*S=4096, N=E, K=D
    gemm_nt_kernel<<<dim3((Bn * S) / BM, E / BN, 1), 256, 0, stream>>>(
        lhs, W, proj, Bn * S, E, D, 0, 0, 0, bias, 1);

    // 2) scores[b] = label @ proj[b]^T: M=L, N=S, K=E  (into weights buf)
    gemm_nt_kernel<<<dim3((L + BM - 1) / BM, S / BN, Bn), 256, 0, stream>>>(
        label, proj, weights, L, S, E,
        0, (long long)S * E, (long long)L * S, nullptr, 0);

    // 3) softmax over L (in-place in weights buf)
    softmax_part_kernel<<<dim3(S / 256, SM_CH, Bn), 256, 0, stream>>>(
        weights, pm, ps, L, S, chlen);
    softmax_merge_kernel<<<dim3(S / 256, Bn), 256, 0, stream>>>(
        pm, ps, fm, fsinv, S);
    softmax_write_kernel<<<dim3(S / 256, SM_CH, Bn), 256, 0, stream>>>(
        weights, fm, fsinv, L, S, chlen);

    // 4) attn[b] = weights[b] @ lhs[b]: M=L, N=D, K=S
    gemm_nn_kernel<<<dim3((L + BM - 1) / BM, D / BN, Bn), 256, 0, stream>>>(
        weights, lhs, attn, L, D, S,
        (long long)L * S, (long long)S * D, (long long)L * D);
}

// Round 3
// 345.185 us; speedup vs baseline: 2.5235x; 2.5235x over previous
//
#include <hip/hip_runtime.h>
#include <hip/hip_bf16.h>
#include <cmath>

typedef __attribute__((ext_vector_type(8))) short short8;
typedef __attribute__((ext_vector_type(4))) float f32x4;

#define SM_CH 32

__device__ inline ushort f2bf(float x) {
    union { float f; unsigned u; } v; v.f = x;
    unsigned r = v.u + 0x7FFF + ((v.u >> 16) & 1);   // RNE
    return (ushort)(r >> 16);
}

// Truncation split: x ~= hi + lo, |x - hi - lo| <= ~2^-16 |x|
__device__ inline void split2(float x, ushort& hi, ushort& lo) {
    union { float f; unsigned u; } v; v.f = x;
    hi = (ushort)(v.u >> 16);
    union { float f; unsigned u; } h; h.u = v.u & 0xFFFF0000u;
    union { float f; unsigned u; } d; d.f = x - h.f;
    lo = (ushort)(d.u >> 16);
}

// byte offset within one [128 x 128B] LDS plane, XOR-swizzled.
__device__ inline int swz(int row, int byte_in_row) {
    return row * 128 + (byte_in_row ^ ((row & 7) << 4));
}

// ---------------------------------------------------------------------------
// Split-precision MFMA NT GEMM: C[m,n] = epi( sum_k A[m,k]*B[n,k] )
// A is f32, split into (hi,lo) bf16 planes at staging (always).
// TB=float  -> B also split, 3-term MFMA (hi*hi + hi*lo + lo*hi)
// TB=ushort -> B is pre-quantized bf16, 2-term MFMA (hi*b + lo*b)
// 128x128 tile, BK=64, 4 waves of 64x64, v_mfma_f32_16x16x32_bf16.
// Dynamic LDS: 4 planes (64KB) if split-B else 3 planes (48KB).
// ---------------------------------------------------------------------------
template<typename TB, bool TANH_BIAS>
__global__ __launch_bounds__(256) void mfma_nt(
    const float* __restrict__ Ab, const TB* __restrict__ Bb,
    float* __restrict__ Cb, const float* __restrict__ bias,
    int M, int N, int K,
    long long sA, long long sB, long long sC)
{
    constexpr bool SPLIT_B = __is_same(TB, float);
    extern __shared__ char smem[];
    char* Ah = smem;                // each plane: 128 rows x 128 bytes = 16KB
    char* Al = smem + 16384;
    char* Bh = smem + 32768;
    char* Bl = smem + 49152;        // used only when SPLIT_B

    const int t  = threadIdx.x;
    const int bm = blockIdx.x * 128;
    const int bn = blockIdx.y * 128;
    const long long z = blockIdx.z;

    const float* A = Ab + z * sA;
    const TB*    B = Bb + z * sB;

    const int srow = t >> 1;
    const int skh  = (t & 1) * 32;   // element offset of this thread's k-half
    const float* ap = A + (long long)min(bm + srow, M - 1) * K + skh;
    const TB*    bp = B + (long long)min(bn + srow, N - 1) * K + skh;

    const int lane = t & 63;
    const int w    = t >> 6;
    const int wm   = (w >> 1) * 64;
    const int wn   = (w & 1) * 64;
    const int lrow = lane & 15;
    const int kg16 = (lane >> 4) * 16;   // byte offset of lane's 8-elem k-group

    f32x4 acc[4][4] = {};

    for (int k0 = 0; k0 < K; k0 += 64) {
        // ---- stage A: split f32 -> hi/lo bf16 planes ----
        #pragma unroll
        for (int j = 0; j < 4; ++j) {
            float xs[8];
            *(float4*)&xs[0] = *(const float4*)(ap + k0 + j * 8);
            *(float4*)&xs[4] = *(const float4*)(ap + k0 + j * 8 + 4);
            ushort oh[8], ol[8];
            #pragma unroll
            for (int i = 0; i < 8; ++i) split2(xs[i], oh[i], ol[i]);
            const int off = swz(srow, skh * 2 + j * 16);
            *(uint4*)(Ah + off) = *(uint4*)oh;
            *(uint4*)(Al + off) = *(uint4*)ol;
        }
        // ---- stage B ----
        #pragma unroll
        for (int j = 0; j < 4; ++j) {
            const int off = swz(srow, skh * 2 + j * 16);
            if constexpr (SPLIT_B) {
                float xs[8];
                *(float4*)&xs[0] = *(const float4*)(bp + k0 + j * 8);
                *(float4*)&xs[4] = *(const float4*)(bp + k0 + j * 8 + 4);
                ushort oh[8], ol[8];
                #pragma unroll
                for (int i = 0; i < 8; ++i) split2(xs[i], oh[i], ol[i]);
                *(uint4*)(Bh + off) = *(uint4*)oh;
                *(uint4*)(Bl + off) = *(uint4*)ol;
            } else {
                *(uint4*)(Bh + off) = *(const uint4*)(bp + k0 + j * 8);
            }
        }
        __syncthreads();

        // ---- compute: 2 k-substeps of 32 ----
        #pragma unroll
        for (int kk = 0; kk < 2; ++kk) {
            short8 ah[4], al[4];
            #pragma unroll
            for (int mi = 0; mi < 4; ++mi) {
                const int off = swz(wm + mi * 16 + lrow, kk * 64 + kg16);
                ah[mi] = *(const short8*)(Ah + off);
                al[mi] = *(const short8*)(Al + off);
            }
            #pragma unroll
            for (int ni = 0; ni < 4; ++ni) {
                const int off = swz(wn + ni * 16 + lrow, kk * 64 + kg16);
                short8 bh = *(const short8*)(Bh + off);
                if constexpr (SPLIT_B) {
                    short8 bl = *(const short8*)(Bl + off);
                    #pragma unroll
                    for (int mi = 0; mi < 4; ++mi) {
                        acc[mi][ni] = __builtin_amdgcn_mfma_f32_16x16x32_bf16(al[mi], bh, acc[mi][ni], 0, 0, 0);
                        acc[mi][ni] = __builtin_amdgcn_mfma_f32_16x16x32_bf16(ah[mi], bl, acc[mi][ni], 0, 0, 0);
                        acc[mi][ni] = __builtin_amdgcn_mfma_f32_16x16x32_bf16(ah[mi], bh, acc[mi][ni], 0, 0, 0);
                    }
                } else {
                    #pragma unroll
                    for (int mi = 0; mi < 4; ++mi) {
                        acc[mi][ni] = __builtin_amdgcn_mfma_f32_16x16x32_bf16(al[mi], bh, acc[mi][ni], 0, 0, 0);
                        acc[mi][ni] = __builtin_amdgcn_mfma_f32_16x16x32_bf16(ah[mi], bh, acc[mi][ni], 0, 0, 0);
                    }
                }
            }
        }
        __syncthreads();
    }

    // ---- epilogue: D frag col = lane&15, row = (lane>>4)*4 + r ----
    float* C = Cb + z * sC;
    const int r0 = bm + wm + (lane >> 4) * 4;
    const int c0 = bn + wn + (lane & 15);
    #pragma unroll
    for (int ni = 0; ni < 4; ++ni) {
        const int col = c0 + ni * 16;
        const float bv = TANH_BIAS ? bias[col] : 0.f;
        #pragma unroll
        for (int mi = 0; mi < 4; ++mi) {
            #pragma unroll
            for (int r = 0; r < 4; ++r) {
                const int row = r0 + mi * 16 + r;
                if (row < M) {
                    float x = acc[mi][ni][r];
                    if constexpr (TANH_BIAS) x = tanhf(x + bv);
                    C[(long long)row * N + col] = x;
                }
            }
        }
    }
}

// ---------------------------------------------------------------------------
// lhs [B,S,D] f32  ->  lhsT [B,D,S] bf16 (hi plane only)
// ---------------------------------------------------------------------------
__global__ __launch_bounds__(256) void transpose_bf16_kernel(
    const float* __restrict__ in, ushort* __restrict__ out, int S, int D)
{
    __shared__ float tile[32][33];
    const int b = blockIdx.z;
    const int s0 = blockIdx.x * 32, d0 = blockIdx.y * 32;
    const int tx = threadIdx.x & 31, ty = threadIdx.x >> 5;
    const float* ip = in + (long long)b * S * D;
    #pragma unroll
    for (int i = 0; i < 32; i += 8)
        tile[ty + i][tx] = ip[(long long)(s0 + ty + i) * D + d0 + tx];
    __syncthreads();
    ushort* op = out + (long long)b * S * D;
    #pragma unroll
    for (int i = 0; i < 32; i += 8)
        op[(long long)(d0 + ty + i) * S + s0 + tx] = f2bf(tile[tx][ty + i]);
}

// ---------------------------------------------------------------------------
// Softmax over L of scores [B,L,S] (in place), 3 passes.
// ---------------------------------------------------------------------------
__global__ __launch_bounds__(256) void softmax_part_kernel(
    const float* __restrict__ scores, float* __restrict__ pm,
    float* __restrict__ ps, int L, int S, int chlen)
{
    int s = blockIdx.x * 256 + threadIdx.x;
    int c = blockIdx.y;
    int b = blockIdx.z;
    int l0 = c * chlen;
    int l1 = min(L, l0 + chlen);
    const float* p = scores + (long long)b * L * S + s;
    float m = -INFINITY, sum = 0.f;
    for (int l = l0; l < l1; ++l) {
        float x = p[(long long)l * S];
        float nm = fmaxf(m, x);
        sum = sum * __expf(m - nm) + __expf(x - nm);
        m = nm;
    }
    int idx = (b * SM_CH + c) * S + s;
    pm[idx] = m;
    ps[idx] = sum;
}

__global__ __launch_bounds__(256) void softmax_merge_kernel(
    const float* __restrict__ pm, const float* __restrict__ ps,
    float* __restrict__ fm, float* __restrict__ fsinv, int S)
{
    int s = blockIdx.x * 256 + threadIdx.x;
    int b = blockIdx.y;
    float m = -INFINITY;
    #pragma unroll
    for (int c = 0; c < SM_CH; ++c)
        m = fmaxf(m, pm[(b * SM_CH + c) * S + s]);
    float sum = 0.f;
    #pragma unroll
    for (int c = 0; c < SM_CH; ++c)
        sum += ps[(b * SM_CH + c) * S + s] * __expf(pm[(b * SM_CH + c) * S + s] - m);
    fm[b * S + s] = m;
    fsinv[b * S + s] = 1.f / sum;
}

__global__ __launch_bounds__(256) void softmax_write_kernel(
    float* __restrict__ scores, const float* __restrict__ fm,
    const float* __restrict__ fsinv, int L, int S, int chlen)
{
    int s = blockIdx.x * 256 + threadIdx.x;
    int c = blockIdx.y;
    int b = blockIdx.z;
    float m   = fm[b * S + s];
    float inv = fsinv[b * S + s];
    float* p = scores + (long long)b * L * S + s;
    int l0 = c * chlen;
    int l1 = min(L, l0 + chlen);
    for (int l = l0; l < l1; ++l) {
        float x = p[(long long)l * S];
        p[(long long)l * S] = __expf(x - m) * inv;
    }
}

extern "C" void kernel_launch(void* const* d_in, const int* in_sizes, int n_in,
                              void* d_out, int out_size, void* d_ws, size_t ws_size,
                              hipStream_t stream)
{
    const int Bn = 8, S = 512, D = 768, E = 768, L = 4000;
    const float* lhs   = (const float*)d_in[0];   // [B,S,D]
    const float* label = (const float*)d_in[1];   // [L,E]
    const float* W     = (const float*)d_in[2];   // [E,D]
    const float* bias  = (const float*)d_in[3];   // [E]

    float* weights = (float*)d_out;                          // [B,L,S]
    float* attn    = (float*)d_out + (long long)Bn * L * S;  // [B,L,D]

    // ws: proj f32 12.58MB | lhsT bf16 6.29MB | softmax partials ~0.6MB
    float*  proj  = (float*)d_ws;                             // [B*S, E]
    ushort* lhsT  = (ushort*)(proj + (long long)Bn * S * E);  // [B, D, S]
    float*  pm    = (float*)(lhsT + (long long)Bn * D * S);
    float*  ps    = pm + (long long)Bn * SM_CH * S;
    float*  fm    = ps + (long long)Bn * SM_CH * S;
    float*  fsinv = fm + (long long)Bn * S;

    const int chlen = (L + SM_CH - 1) / SM_CH;  // 125

    // 0) lhsT = transpose(lhs) in bf16  [B,D,S]
    transpose_bf16_kernel<<<dim3(S / 32, D / 32, Bn), 256, 0, stream>>>(
        lhs, lhsT, S, D);

    // 1) proj = tanh(lhs @ W^T + bias), f32: M=4096, N=E, K=D  (3-term split)
    mfma_nt<float, true><<<dim3((Bn * S) / 128, E / 128, 1), 256, 65536, stream>>>(
        lhs, W, proj, bias, Bn * S, E, D, 0, 0, 0);

    // 2) scores[b] = label @ proj[b]^T: M=L, N=S, K=E  (3-term split)
    mfma_nt<float, false><<<dim3((L + 127) / 128, S / 128, Bn), 256, 65536, stream>>>(
        label, proj, weights, nullptr, L, S, E,
        0, (long long)S * E, (long long)L * S);

    // 3) softmax over L, in place
    softmax_part_kernel<<<dim3(S / 256, SM_CH, Bn), 256, 0, stream>>>(
        weights, pm, ps, L, S, chlen);
    softmax_merge_kernel<<<dim3(S / 256, Bn), 256, 0, stream>>>(
        pm, ps, fm, fsinv, S);
    softmax_write_kernel<<<dim3(S / 256, SM_CH, Bn), 256, 0, stream>>>(
        weights, fm, fsinv, L, S, chlen);

    // 4) attn[b] = weights[b] @ lhsT[b]^T: M=L, N=D, K=S  (2-term, B bf16)
    mfma_nt<ushort, false><<<dim3((L + 127) / 128, D / 128, Bn), 256, 49152, stream>>>(
        weights, lhsT, attn, nullptr, L, D, S,
        (long long)L * S, (long long)D * S, (long long)L * D);
}

// Round 4
// 322.679 us; speedup vs baseline: 2.6995x; 1.0697x over previous
//
#include <hip/hip_runtime.h>
#include <hip/hip_bf16.h>
#include <cmath>

typedef __attribute__((ext_vector_type(8))) short short8;
typedef __attribute__((ext_vector_type(4))) float f32x4;

#define SM_CH 32

__device__ inline ushort f2bf(float x) {
    union { float f; unsigned u; } v; v.f = x;
    unsigned r = v.u + 0x7FFF + ((v.u >> 16) & 1);   // RNE
    return (ushort)(r >> 16);
}

// Truncation split: x ~= hi + lo
__device__ inline void split2(float x, ushort& hi, ushort& lo) {
    union { float f; unsigned u; } v; v.f = x;
    hi = (ushort)(v.u >> 16);
    union { float f; unsigned u; } h; h.u = v.u & 0xFFFF0000u;
    union { float f; unsigned u; } d; d.f = x - h.f;
    lo = (ushort)(d.u >> 16);
}

// byte offset within one [128 x 128B] LDS plane, XOR-swizzled.
__device__ inline int swz(int row, int byte_in_row) {
    return row * 128 + (byte_in_row ^ ((row & 7) << 4));
}

// async global->LDS, 16B per lane. lds base must be wave-uniform; HW adds lane*16.
__device__ inline void gload16(const void* g, void* lds) {
    __builtin_amdgcn_global_load_lds(
        (const __attribute__((address_space(1))) unsigned int*)g,
        (__attribute__((address_space(3))) unsigned int*)lds, 16, 0, 0);
}

// T1: bijective XCD-aware block remap (requires nwg % 8 == 0).
__device__ inline void xcd_remap(int& bx, int& by, int& bz) {
    unsigned nx = gridDim.x, ny = gridDim.y;
    unsigned nwg = nx * ny * gridDim.z;
    unsigned id = blockIdx.x + nx * (blockIdx.y + ny * blockIdx.z);
    unsigned q = nwg >> 3;
    unsigned s = (id & 7) * q + (id >> 3);
    bx = s % nx; unsigned r = s / nx;
    by = r % ny; bz = r / ny;
}

// ---------------------------------------------------------------------------
// proj GEMM: projH/projL = split2(tanh(lhs @ W^T + bias))
// A=lhs f32 [4096,768], B=W f32 [768,768]; 3-term split MFMA; 64KB LDS.
// ---------------------------------------------------------------------------
__global__ __launch_bounds__(256) void mfma_proj(
    const float* __restrict__ Ab, const float* __restrict__ Bb,
    ushort* __restrict__ CH, ushort* __restrict__ CL,
    const float* __restrict__ bias, int M, int N, int K)
{
    extern __shared__ char smem[];
    char* Ah = smem;
    char* Al = smem + 16384;
    char* Bh = smem + 32768;
    char* Bl = smem + 49152;

    int bx, by, bz; xcd_remap(bx, by, bz);
    const int bm = bx * 128;
    const int bn = by * 128;

    const int t  = threadIdx.x;
    const int srow = t >> 1;
    const int skh  = (t & 1) * 32;
    const float* ap = Ab + (long long)min(bm + srow, M - 1) * K + skh;
    const float* bp = Bb + (long long)min(bn + srow, N - 1) * K + skh;

    const int lane = t & 63;
    const int w    = t >> 6;
    const int wm   = (w >> 1) * 64;
    const int wn   = (w & 1) * 64;
    const int lrow = lane & 15;
    const int kg16 = (lane >> 4) * 16;

    f32x4 acc[4][4] = {};

    for (int k0 = 0; k0 < K; k0 += 64) {
        #pragma unroll
        for (int j = 0; j < 4; ++j) {
            float xs[8];
            *(float4*)&xs[0] = *(const float4*)(ap + k0 + j * 8);
            *(float4*)&xs[4] = *(const float4*)(ap + k0 + j * 8 + 4);
            ushort oh[8], ol[8];
            #pragma unroll
            for (int i = 0; i < 8; ++i) split2(xs[i], oh[i], ol[i]);
            const int off = swz(srow, skh * 2 + j * 16);
            *(uint4*)(Ah + off) = *(uint4*)oh;
            *(uint4*)(Al + off) = *(uint4*)ol;
        }
        #pragma unroll
        for (int j = 0; j < 4; ++j) {
            float xs[8];
            *(float4*)&xs[0] = *(const float4*)(bp + k0 + j * 8);
            *(float4*)&xs[4] = *(const float4*)(bp + k0 + j * 8 + 4);
            ushort oh[8], ol[8];
            #pragma unroll
            for (int i = 0; i < 8; ++i) split2(xs[i], oh[i], ol[i]);
            const int off = swz(srow, skh * 2 + j * 16);
            *(uint4*)(Bh + off) = *(uint4*)oh;
            *(uint4*)(Bl + off) = *(uint4*)ol;
        }
        __syncthreads();

        #pragma unroll
        for (int kk = 0; kk < 2; ++kk) {
            short8 ah[4], al[4];
            #pragma unroll
            for (int mi = 0; mi < 4; ++mi) {
                const int off = swz(wm + mi * 16 + lrow, kk * 64 + kg16);
                ah[mi] = *(const short8*)(Ah + off);
                al[mi] = *(const short8*)(Al + off);
            }
            #pragma unroll
            for (int ni = 0; ni < 4; ++ni) {
                const int off = swz(wn + ni * 16 + lrow, kk * 64 + kg16);
                short8 bh = *(const short8*)(Bh + off);
                short8 bl = *(const short8*)(Bl + off);
                #pragma unroll
                for (int mi = 0; mi < 4; ++mi) {
                    acc[mi][ni] = __builtin_amdgcn_mfma_f32_16x16x32_bf16(al[mi], bh, acc[mi][ni], 0, 0, 0);
                    acc[mi][ni] = __builtin_amdgcn_mfma_f32_16x16x32_bf16(ah[mi], bl, acc[mi][ni], 0, 0, 0);
                    acc[mi][ni] = __builtin_amdgcn_mfma_f32_16x16x32_bf16(ah[mi], bh, acc[mi][ni], 0, 0, 0);
                }
            }
        }
        __syncthreads();
    }

    const int r0 = bm + wm + (lane >> 4) * 4;
    const int c0 = bn + wn + (lane & 15);
    #pragma unroll
    for (int ni = 0; ni < 4; ++ni) {
        const int col = c0 + ni * 16;
        const float bv = bias[col];
        #pragma unroll
        for (int mi = 0; mi < 4; ++mi) {
            #pragma unroll
            for (int r = 0; r < 4; ++r) {
                const int row = r0 + mi * 16 + r;
                if (row < M) {
                    float x = tanhf(acc[mi][ni][r] + bv);
                    ushort h, l;
                    split2(x, h, l);
                    CH[(long long)row * N + col] = h;
                    CL[(long long)row * N + col] = l;
                }
            }
        }
    }
}

// ---------------------------------------------------------------------------
// scores GEMM: weights[b] = label @ proj[b]^T, 3-term split.
// A = label f32 (reg-staged split), B = projH/projL bf16 planes (gload_lds).
// ---------------------------------------------------------------------------
__global__ __launch_bounds__(256) void mfma_scores(
    const float* __restrict__ label, const ushort* __restrict__ BHb,
    const ushort* __restrict__ BLb, float* __restrict__ Cb,
    int M, int N, int K, long long sB, long long sC)
{
    extern __shared__ char smem[];
    char* Ah = smem;
    char* Al = smem + 16384;
    char* Bh = smem + 32768;
    char* Bl = smem + 49152;

    int bx, by, bz; xcd_remap(bx, by, bz);
    const int bm = bx * 128;
    const int bn = by * 128;
    const long long z = bz;

    const ushort* BH = BHb + z * sB;
    const ushort* BL = BLb + z * sB;

    const int t  = threadIdx.x;
    const int lane = t & 63;
    const int w    = t >> 6;

    // A reg-staging
    const int srow = t >> 1;
    const int skh  = (t & 1) * 32;
    const float* ap = label + (long long)min(bm + srow, M - 1) * K + skh;

    // B gload_lds: lane's fixed (row, col) within the tile, inverse-swizzled src
    const int lr  = lane >> 3;                 // 0..7
    const int lc8 = 8 * ((lane & 7) ^ lr);     // element offset in row
    const ushort* bh_src[4]; const ushort* bl_src[4];
    int ldsB[4];
    #pragma unroll
    for (int i = 0; i < 4; ++i) {
        const int row = w * 32 + i * 8 + lr;
        bh_src[i] = BH + (long long)min(bn + row, N - 1) * K + lc8;
        bl_src[i] = BL + (long long)min(bn + row, N - 1) * K + lc8;
        ldsB[i] = w * 4096 + i * 1024;         // wave-uniform base
    }

    const int wm   = (w >> 1) * 64;
    const int wn   = (w & 1) * 64;
    const int lrow = lane & 15;
    const int kg16 = (lane >> 4) * 16;

    f32x4 acc[4][4] = {};

    for (int k0 = 0; k0 < K; k0 += 64) {
        // issue B async loads first
        #pragma unroll
        for (int i = 0; i < 4; ++i) {
            gload16(bh_src[i] + k0, Bh + ldsB[i]);
            gload16(bl_src[i] + k0, Bl + ldsB[i]);
        }
        // A: reg-stage split
        #pragma unroll
        for (int j = 0; j < 4; ++j) {
            float xs[8];
            *(float4*)&xs[0] = *(const float4*)(ap + k0 + j * 8);
            *(float4*)&xs[4] = *(const float4*)(ap + k0 + j * 8 + 4);
            ushort oh[8], ol[8];
            #pragma unroll
            for (int i = 0; i < 8; ++i) split2(xs[i], oh[i], ol[i]);
            const int off = swz(srow, skh * 2 + j * 16);
            *(uint4*)(Ah + off) = *(uint4*)oh;
            *(uint4*)(Al + off) = *(uint4*)ol;
        }
        __syncthreads();

        #pragma unroll
        for (int kk = 0; kk < 2; ++kk) {
            short8 ah[4], al[4];
            #pragma unroll
            for (int mi = 0; mi < 4; ++mi) {
                const int off = swz(wm + mi * 16 + lrow, kk * 64 + kg16);
                ah[mi] = *(const short8*)(Ah + off);
                al[mi] = *(const short8*)(Al + off);
            }
            #pragma unroll
            for (int ni = 0; ni < 4; ++ni) {
                const int off = swz(wn + ni * 16 + lrow, kk * 64 + kg16);
                short8 bh = *(const short8*)(Bh + off);
                short8 bl = *(const short8*)(Bl + off);
                #pragma unroll
                for (int mi = 0; mi < 4; ++mi) {
                    acc[mi][ni] = __builtin_amdgcn_mfma_f32_16x16x32_bf16(al[mi], bh, acc[mi][ni], 0, 0, 0);
                    acc[mi][ni] = __builtin_amdgcn_mfma_f32_16x16x32_bf16(ah[mi], bl, acc[mi][ni], 0, 0, 0);
                    acc[mi][ni] = __builtin_amdgcn_mfma_f32_16x16x32_bf16(ah[mi], bh, acc[mi][ni], 0, 0, 0);
                }
            }
        }
        __syncthreads();
    }

    float* C = Cb + z * sC;
    const int r0 = bm + wm + (lane >> 4) * 4;
    const int c0 = bn + wn + (lane & 15);
    #pragma unroll
    for (int ni = 0; ni < 4; ++ni) {
        const int col = c0 + ni * 16;
        #pragma unroll
        for (int mi = 0; mi < 4; ++mi) {
            #pragma unroll
            for (int r = 0; r < 4; ++r) {
                const int row = r0 + mi * 16 + r;
                if (row < M) C[(long long)row * N + col] = acc[mi][ni][r];
            }
        }
    }
}

// ---------------------------------------------------------------------------
// attn GEMM: attn[b] = weights[b] @ lhsT[b]^T, single-term bf16.
// A = weights f32 (reg-staged -> bf16), B = lhsT bf16 (gload_lds). 32KB LDS.
// ---------------------------------------------------------------------------
__global__ __launch_bounds__(256) void mfma_attn(
    const float* __restrict__ Ab, const ushort* __restrict__ Bb,
    float* __restrict__ Cb, int M, int N, int K,
    long long sA, long long sB, long long sC)
{
    extern __shared__ char smem[];
    char* Ah = smem;
    char* Bh = smem + 16384;

    int bx, by, bz; xcd_remap(bx, by, bz);
    const int bm = bx * 128;
    const int bn = by * 128;
    const long long z = bz;

    const float*  A = Ab + z * sA;
    const ushort* B = Bb + z * sB;

    const int t  = threadIdx.x;
    const int lane = t & 63;
    const int w    = t >> 6;

    const int srow = t >> 1;
    const int skh  = (t & 1) * 32;
    const float* ap = A + (long long)min(bm + srow, M - 1) * K + skh;

    const int lr  = lane >> 3;
    const int lc8 = 8 * ((lane & 7) ^ lr);
    const ushort* b_src[4];
    int ldsB[4];
    #pragma unroll
    for (int i = 0; i < 4; ++i) {
        const int row = w * 32 + i * 8 + lr;
        b_src[i] = B + (long long)min(bn + row, N - 1) * K + lc8;
        ldsB[i] = w * 4096 + i * 1024;
    }

    const int wm   = (w >> 1) * 64;
    const int wn   = (w & 1) * 64;
    const int lrow = lane & 15;
    const int kg16 = (lane >> 4) * 16;

    f32x4 acc[4][4] = {};

    for (int k0 = 0; k0 < K; k0 += 64) {
        #pragma unroll
        for (int i = 0; i < 4; ++i)
            gload16(b_src[i] + k0, Bh + ldsB[i]);
        #pragma unroll
        for (int j = 0; j < 4; ++j) {
            float xs[8];
            *(float4*)&xs[0] = *(const float4*)(ap + k0 + j * 8);
            *(float4*)&xs[4] = *(const float4*)(ap + k0 + j * 8 + 4);
            ushort o[8];
            #pragma unroll
            for (int i = 0; i < 8; ++i) o[i] = f2bf(xs[i]);
            *(uint4*)(Ah + swz(srow, skh * 2 + j * 16)) = *(uint4*)o;
        }
        __syncthreads();

        #pragma unroll
        for (int kk = 0; kk < 2; ++kk) {
            short8 ah[4];
            #pragma unroll
            for (int mi = 0; mi < 4; ++mi)
                ah[mi] = *(const short8*)(Ah + swz(wm + mi * 16 + lrow, kk * 64 + kg16));
            #pragma unroll
            for (int ni = 0; ni < 4; ++ni) {
                short8 bh = *(const short8*)(Bh + swz(wn + ni * 16 + lrow, kk * 64 + kg16));
                #pragma unroll
                for (int mi = 0; mi < 4; ++mi)
                    acc[mi][ni] = __builtin_amdgcn_mfma_f32_16x16x32_bf16(ah[mi], bh, acc[mi][ni], 0, 0, 0);
            }
        }
        __syncthreads();
    }

    float* C = Cb + z * sC;
    const int r0 = bm + wm + (lane >> 4) * 4;
    const int c0 = bn + wn + (lane & 15);
    #pragma unroll
    for (int ni = 0; ni < 4; ++ni) {
        const int col = c0 + ni * 16;
        #pragma unroll
        for (int mi = 0; mi < 4; ++mi) {
            #pragma unroll
            for (int r = 0; r < 4; ++r) {
                const int row = r0 + mi * 16 + r;
                if (row < M) C[(long long)row * N + col] = acc[mi][ni][r];
            }
        }
    }
}

// ---------------------------------------------------------------------------
// lhs [B,S,D] f32  ->  lhsT [B,D,S] bf16
// ---------------------------------------------------------------------------
__global__ __launch_bounds__(256) void transpose_bf16_kernel(
    const float* __restrict__ in, ushort* __restrict__ out, int S, int D)
{
    __shared__ float tile[32][33];
    const int b = blockIdx.z;
    const int s0 = blockIdx.x * 32, d0 = blockIdx.y * 32;
    const int tx = threadIdx.x & 31, ty = threadIdx.x >> 5;
    const float* ip = in + (long long)b * S * D;
    #pragma unroll
    for (int i = 0; i < 32; i += 8)
        tile[ty + i][tx] = ip[(long long)(s0 + ty + i) * D + d0 + tx];
    __syncthreads();
    ushort* op = out + (long long)b * S * D;
    #pragma unroll
    for (int i = 0; i < 32; i += 8)
        op[(long long)(d0 + ty + i) * S + s0 + tx] = f2bf(tile[tx][ty + i]);
}

// ---------------------------------------------------------------------------
// Softmax over L of scores [B,L,S] (in place), 3 passes.
// ---------------------------------------------------------------------------
__global__ __launch_bounds__(256) void softmax_part_kernel(
    const float* __restrict__ scores, float* __restrict__ pm,
    float* __restrict__ ps, int L, int S, int chlen)
{
    int s = blockIdx.x * 256 + threadIdx.x;
    int c = blockIdx.y;
    int b = blockIdx.z;
    int l0 = c * chlen;
    int l1 = min(L, l0 + chlen);
    const float* p = scores + (long long)b * L * S + s;
    float m = -INFINITY, sum = 0.f;
    for (int l = l0; l < l1; ++l) {
        float x = p[(long long)l * S];
        float nm = fmaxf(m, x);
        sum = sum * __expf(m - nm) + __expf(x - nm);
        m = nm;
    }
    int idx = (b * SM_CH + c) * S + s;
    pm[idx] = m;
    ps[idx] = sum;
}

__global__ __launch_bounds__(256) void softmax_merge_kernel(
    const float* __restrict__ pm, const float* __restrict__ ps,
    float* __restrict__ fm, float* __restrict__ fsinv, int S)
{
    int s = blockIdx.x * 256 + threadIdx.x;
    int b = blockIdx.y;
    float m = -INFINITY;
    #pragma unroll
    for (int c = 0; c < SM_CH; ++c)
        m = fmaxf(m, pm[(b * SM_CH + c) * S + s]);
    float sum = 0.f;
    #pragma unroll
    for (int c = 0; c < SM_CH; ++c)
        sum += ps[(b * SM_CH + c) * S + s] * __expf(pm[(b * SM_CH + c) * S + s] - m);
    fm[b * S + s] = m;
    fsinv[b * S + s] = 1.f / sum;
}

__global__ __launch_bounds__(256) void softmax_write_kernel(
    float* __restrict__ scores, const float* __restrict__ fm,
    const float* __restrict__ fsinv, int L, int S, int chlen)
{
    int s = blockIdx.x * 256 + threadIdx.x;
    int c = blockIdx.y;
    int b = blockIdx.z;
    float m   = fm[b * S + s];
    float inv = fsinv[b * S + s];
    float* p = scores + (long long)b * L * S + s;
    int l0 = c * chlen;
    int l1 = min(L, l0 + chlen);
    for (int l = l0; l < l1; ++l) {
        float x = p[(long long)l * S];
        p[(long long)l * S] = __expf(x - m) * inv;
    }
}

extern "C" void kernel_launch(void* const* d_in, const int* in_sizes, int n_in,
                              void* d_out, int out_size, void* d_ws, size_t ws_size,
                              hipStream_t stream)
{
    const int Bn = 8, S = 512, D = 768, E = 768, L = 4000;
    const float* lhs   = (const float*)d_in[0];   // [B,S,D]
    const float* label = (const float*)d_in[1];   // [L,E]
    const float* W     = (const float*)d_in[2];   // [E,D]
    const float* bias  = (const float*)d_in[3];   // [E]

    float* weights = (float*)d_out;                          // [B,L,S]
    float* attn    = (float*)d_out + (long long)Bn * L * S;  // [B,L,D]

    // ws: projH 6.3MB | projL 6.3MB | lhsT 6.3MB | softmax partials ~0.6MB
    ushort* projH = (ushort*)d_ws;                               // [B,S,E]
    ushort* projL = projH + (long long)Bn * S * E;               // [B,S,E]
    ushort* lhsT  = projL + (long long)Bn * S * E;               // [B,D,S]
    float*  pm    = (float*)(lhsT + (long long)Bn * D * S);
    float*  ps    = pm + (long long)Bn * SM_CH * S;
    float*  fm    = ps + (long long)Bn * SM_CH * S;
    float*  fsinv = fm + (long long)Bn * S;

    const int chlen = (L + SM_CH - 1) / SM_CH;  // 125

    // 0) lhsT = transpose(lhs) in bf16  [B,D,S]
    transpose_bf16_kernel<<<dim3(S / 32, D / 32, Bn), 256, 0, stream>>>(
        lhs, lhsT, S, D);

    // 1) projH/L = split(tanh(lhs @ W^T + bias)): M=4096, N=E, K=D
    mfma_proj<<<dim3((Bn * S) / 128, E / 128, 1), 256, 65536, stream>>>(
        lhs, W, projH, projL, bias, Bn * S, E, D);

    // 2) scores[b] = label @ proj[b]^T: M=L, N=S, K=E (3-term)
    mfma_scores<<<dim3((L + 127) / 128, S / 128, Bn), 256, 65536, stream>>>(
        label, projH, projL, weights, L, S, E,
        (long long)S * E, (long long)L * S);

    // 3) softmax over L, in place
    softmax_part_kernel<<<dim3(S / 256, SM_CH, Bn), 256, 0, stream>>>(
        weights, pm, ps, L, S, chlen);
    softmax_merge_kernel<<<dim3(S / 256, Bn), 256, 0, stream>>>(
        pm, ps, fm, fsinv, S);
    softmax_write_kernel<<<dim3(S / 256, SM_CH, Bn), 256, 0, stream>>>(
        weights, fm, fsinv, L, S, chlen);

    // 4) attn[b] = weights[b] @ lhsT[b]^T: M=L, N=D, K=S (1-term)
    mfma_attn<<<dim3((L + 127) / 128, D / 128, Bn), 256, 32768, stream>>>(
        weights, lhsT, attn, L, D, S,
        (long long)L * S, (long long)D * S, (long long)L * D);
}

// Round 5
// 286.098 us; speedup vs baseline: 3.0447x; 1.1279x over previous
//
#include <hip/hip_runtime.h>
#include <hip/hip_bf16.h>
#include <cmath>

typedef __attribute__((ext_vector_type(8))) short short8;
typedef __attribute__((ext_vector_type(4))) float f32x4;

#define SM_CH 32

__device__ inline ushort f2bf(float x) {
    union { float f; unsigned u; } v; v.f = x;
    unsigned r = v.u + 0x7FFF + ((v.u >> 16) & 1);   // RNE
    return (ushort)(r >> 16);
}

// Truncation split: x ~= hi + lo
__device__ inline void split2(float x, ushort& hi, ushort& lo) {
    union { float f; unsigned u; } v; v.f = x;
    hi = (ushort)(v.u >> 16);
    union { float f; unsigned u; } h; h.u = v.u & 0xFFFF0000u;
    union { float f; unsigned u; } d; d.f = x - h.f;
    lo = (ushort)(d.u >> 16);
}

// byte offset within one [128 x 128B] LDS plane, XOR-swizzled.
__device__ inline int swz(int row, int byte_in_row) {
    return row * 128 + (byte_in_row ^ ((row & 7) << 4));
}

// async global->LDS, 16B per lane. lds base wave-uniform; HW adds lane*16.
__device__ inline void gload16(const void* g, void* lds) {
    __builtin_amdgcn_global_load_lds(
        (const __attribute__((address_space(1))) unsigned int*)g,
        (__attribute__((address_space(3))) unsigned int*)lds, 16, 0, 0);
}

// T1: bijective XCD-aware block remap (requires nwg % 8 == 0).
__device__ inline void xcd_remap(int& bx, int& by, int& bz) {
    unsigned nx = gridDim.x, ny = gridDim.y;
    unsigned nwg = nx * ny * gridDim.z;
    unsigned id = blockIdx.x + nx * (blockIdx.y + ny * blockIdx.z);
    unsigned q = nwg >> 3;
    unsigned s = (id & 7) * q + (id >> 3);
    bx = s % nx; unsigned r = s / nx;
    by = r % ny; bz = r / ny;
}

// ---------------------------------------------------------------------------
// split f32 array -> hi/lo bf16 planes (one-shot, for label)
// ---------------------------------------------------------------------------
__global__ __launch_bounds__(256) void split_planes_kernel(
    const float* __restrict__ in, ushort* __restrict__ H,
    ushort* __restrict__ L, long long n4)
{
    long long i = (long long)blockIdx.x * 256 + threadIdx.x;
    if (i >= n4) return;
    float4 v = *(const float4*)(in + i * 4);
    ushort h[4], l[4];
    split2(v.x, h[0], l[0]); split2(v.y, h[1], l[1]);
    split2(v.z, h[2], l[2]); split2(v.w, h[3], l[3]);
    *(ushort4*)(H + i * 4) = *(ushort4*)h;
    *(ushort4*)(L + i * 4) = *(ushort4*)l;
}

// ---------------------------------------------------------------------------
// proj GEMM: projH/projL = split2(tanh(lhs @ W^T + bias)); 3-term split.
// ---------------------------------------------------------------------------
__global__ __launch_bounds__(256) void mfma_proj(
    const float* __restrict__ Ab, const float* __restrict__ Bb,
    ushort* __restrict__ CH, ushort* __restrict__ CL,
    const float* __restrict__ bias, int M, int N, int K)
{
    extern __shared__ char smem[];
    char* Ah = smem;
    char* Al = smem + 16384;
    char* Bh = smem + 32768;
    char* Bl = smem + 49152;

    int bx, by, bz; xcd_remap(bx, by, bz);
    const int bm = bx * 128;
    const int bn = by * 128;

    const int t  = threadIdx.x;
    const int srow = t >> 1;
    const int skh  = (t & 1) * 32;
    const float* ap = Ab + (long long)min(bm + srow, M - 1) * K + skh;
    const float* bp = Bb + (long long)min(bn + srow, N - 1) * K + skh;

    const int lane = t & 63;
    const int w    = t >> 6;
    const int wm   = (w >> 1) * 64;
    const int wn   = (w & 1) * 64;
    const int lrow = lane & 15;
    const int kg16 = (lane >> 4) * 16;

    f32x4 acc[4][4] = {};

    for (int k0 = 0; k0 < K; k0 += 64) {
        #pragma unroll
        for (int j = 0; j < 4; ++j) {
            float xs[8];
            *(float4*)&xs[0] = *(const float4*)(ap + k0 + j * 8);
            *(float4*)&xs[4] = *(const float4*)(ap + k0 + j * 8 + 4);
            ushort oh[8], ol[8];
            #pragma unroll
            for (int i = 0; i < 8; ++i) split2(xs[i], oh[i], ol[i]);
            const int off = swz(srow, skh * 2 + j * 16);
            *(uint4*)(Ah + off) = *(uint4*)oh;
            *(uint4*)(Al + off) = *(uint4*)ol;
        }
        #pragma unroll
        for (int j = 0; j < 4; ++j) {
            float xs[8];
            *(float4*)&xs[0] = *(const float4*)(bp + k0 + j * 8);
            *(float4*)&xs[4] = *(const float4*)(bp + k0 + j * 8 + 4);
            ushort oh[8], ol[8];
            #pragma unroll
            for (int i = 0; i < 8; ++i) split2(xs[i], oh[i], ol[i]);
            const int off = swz(srow, skh * 2 + j * 16);
            *(uint4*)(Bh + off) = *(uint4*)oh;
            *(uint4*)(Bl + off) = *(uint4*)ol;
        }
        __syncthreads();

        #pragma unroll
        for (int kk = 0; kk < 2; ++kk) {
            short8 ah[4], al[4];
            #pragma unroll
            for (int mi = 0; mi < 4; ++mi) {
                const int off = swz(wm + mi * 16 + lrow, kk * 64 + kg16);
                ah[mi] = *(const short8*)(Ah + off);
                al[mi] = *(const short8*)(Al + off);
            }
            #pragma unroll
            for (int ni = 0; ni < 4; ++ni) {
                const int off = swz(wn + ni * 16 + lrow, kk * 64 + kg16);
                short8 bh = *(const short8*)(Bh + off);
                short8 bl = *(const short8*)(Bl + off);
                #pragma unroll
                for (int mi = 0; mi < 4; ++mi) {
                    acc[mi][ni] = __builtin_amdgcn_mfma_f32_16x16x32_bf16(al[mi], bh, acc[mi][ni], 0, 0, 0);
                    acc[mi][ni] = __builtin_amdgcn_mfma_f32_16x16x32_bf16(ah[mi], bl, acc[mi][ni], 0, 0, 0);
                    acc[mi][ni] = __builtin_amdgcn_mfma_f32_16x16x32_bf16(ah[mi], bh, acc[mi][ni], 0, 0, 0);
                }
            }
        }
        __syncthreads();
    }

    const int r0 = bm + wm + (lane >> 4) * 4;
    const int c0 = bn + wn + (lane & 15);
    #pragma unroll
    for (int ni = 0; ni < 4; ++ni) {
        const int col = c0 + ni * 16;
        const float bv = bias[col];
        #pragma unroll
        for (int mi = 0; mi < 4; ++mi) {
            #pragma unroll
            for (int r = 0; r < 4; ++r) {
                const int row = r0 + mi * 16 + r;
                if (row < M) {
                    float x = tanhf(acc[mi][ni][r] + bv);
                    ushort h, l;
                    split2(x, h, l);
                    CH[(long long)row * N + col] = h;
                    CL[(long long)row * N + col] = l;
                }
            }
        }
    }
}

// ---------------------------------------------------------------------------
// scores GEMM (pre-split path): weights[b] = labelHL @ projHL[b]^T, 3-term.
// All 4 planes staged via global_load_lds. Zero VALU in the K-loop.
// ---------------------------------------------------------------------------
__global__ __launch_bounds__(256) void mfma_scores_pre(
    const ushort* __restrict__ AHb, const ushort* __restrict__ ALb,
    const ushort* __restrict__ BHb, const ushort* __restrict__ BLb,
    float* __restrict__ Cb, int M, int N, int K, long long sB, long long sC)
{
    extern __shared__ char smem[];
    char* Ah = smem;
    char* Al = smem + 16384;
    char* Bh = smem + 32768;
    char* Bl = smem + 49152;

    int bx, by, bz; xcd_remap(bx, by, bz);
    const int bm = bx * 128;
    const int bn = by * 128;
    const long long z = bz;

    const ushort* BH = BHb + z * sB;
    const ushort* BL = BLb + z * sB;

    const int t    = threadIdx.x;
    const int lane = t & 63;
    const int w    = t >> 6;

    const int lr  = lane >> 3;
    const int lc8 = 8 * ((lane & 7) ^ lr);   // inverse-swizzled src col
    const ushort *ah_src[4], *al_src[4], *bh_src[4], *bl_src[4];
    int ldsO[4];
    #pragma unroll
    for (int i = 0; i < 4; ++i) {
        const int row = w * 32 + i * 8 + lr;
        ah_src[i] = AHb + (long long)min(bm + row, M - 1) * K + lc8;
        al_src[i] = ALb + (long long)min(bm + row, M - 1) * K + lc8;
        bh_src[i] = BH  + (long long)(bn + row) * K + lc8;
        bl_src[i] = BL  + (long long)(bn + row) * K + lc8;
        ldsO[i] = w * 4096 + i * 1024;
    }

    const int wm   = (w >> 1) * 64;
    const int wn   = (w & 1) * 64;
    const int lrow = lane & 15;
    const int kg16 = (lane >> 4) * 16;

    f32x4 acc[4][4] = {};

    for (int k0 = 0; k0 < K; k0 += 64) {
        #pragma unroll
        for (int i = 0; i < 4; ++i) {
            gload16(ah_src[i] + k0, Ah + ldsO[i]);
            gload16(al_src[i] + k0, Al + ldsO[i]);
            gload16(bh_src[i] + k0, Bh + ldsO[i]);
            gload16(bl_src[i] + k0, Bl + ldsO[i]);
        }
        __syncthreads();

        #pragma unroll
        for (int kk = 0; kk < 2; ++kk) {
            short8 ah[4], al[4];
            #pragma unroll
            for (int mi = 0; mi < 4; ++mi) {
                const int off = swz(wm + mi * 16 + lrow, kk * 64 + kg16);
                ah[mi] = *(const short8*)(Ah + off);
                al[mi] = *(const short8*)(Al + off);
            }
            #pragma unroll
            for (int ni = 0; ni < 4; ++ni) {
                const int off = swz(wn + ni * 16 + lrow, kk * 64 + kg16);
                short8 bh = *(const short8*)(Bh + off);
                short8 bl = *(const short8*)(Bl + off);
                #pragma unroll
                for (int mi = 0; mi < 4; ++mi) {
                    acc[mi][ni] = __builtin_amdgcn_mfma_f32_16x16x32_bf16(al[mi], bh, acc[mi][ni], 0, 0, 0);
                    acc[mi][ni] = __builtin_amdgcn_mfma_f32_16x16x32_bf16(ah[mi], bl, acc[mi][ni], 0, 0, 0);
                    acc[mi][ni] = __builtin_amdgcn_mfma_f32_16x16x32_bf16(ah[mi], bh, acc[mi][ni], 0, 0, 0);
                }
            }
        }
        __syncthreads();
    }

    float* C = Cb + z * sC;
    const int r0 = bm + wm + (lane >> 4) * 4;
    const int c0 = bn + wn + (lane & 15);
    #pragma unroll
    for (int ni = 0; ni < 4; ++ni) {
        const int col = c0 + ni * 16;
        #pragma unroll
        for (int mi = 0; mi < 4; ++mi) {
            #pragma unroll
            for (int r = 0; r < 4; ++r) {
                const int row = r0 + mi * 16 + r;
                if (row < M) C[(long long)row * N + col] = acc[mi][ni][r];
            }
        }
    }
}

// ---------------------------------------------------------------------------
// scores GEMM (fallback, R4): A=label f32 reg-staged split, B planes gload.
// ---------------------------------------------------------------------------
__global__ __launch_bounds__(256) void mfma_scores(
    const float* __restrict__ label, const ushort* __restrict__ BHb,
    const ushort* __restrict__ BLb, float* __restrict__ Cb,
    int M, int N, int K, long long sB, long long sC)
{
    extern __shared__ char smem[];
    char* Ah = smem;
    char* Al = smem + 16384;
    char* Bh = smem + 32768;
    char* Bl = smem + 49152;

    int bx, by, bz; xcd_remap(bx, by, bz);
    const int bm = bx * 128;
    const int bn = by * 128;
    const long long z = bz;

    const ushort* BH = BHb + z * sB;
    const ushort* BL = BLb + z * sB;

    const int t  = threadIdx.x;
    const int lane = t & 63;
    const int w    = t >> 6;

    const int srow = t >> 1;
    const int skh  = (t & 1) * 32;
    const float* ap = label + (long long)min(bm + srow, M - 1) * K + skh;

    const int lr  = lane >> 3;
    const int lc8 = 8 * ((lane & 7) ^ lr);
    const ushort* bh_src[4]; const ushort* bl_src[4];
    int ldsB[4];
    #pragma unroll
    for (int i = 0; i < 4; ++i) {
        const int row = w * 32 + i * 8 + lr;
        bh_src[i] = BH + (long long)min(bn + row, N - 1) * K + lc8;
        bl_src[i] = BL + (long long)min(bn + row, N - 1) * K + lc8;
        ldsB[i] = w * 4096 + i * 1024;
    }

    const int wm   = (w >> 1) * 64;
    const int wn   = (w & 1) * 64;
    const int lrow = lane & 15;
    const int kg16 = (lane >> 4) * 16;

    f32x4 acc[4][4] = {};

    for (int k0 = 0; k0 < K; k0 += 64) {
        #pragma unroll
        for (int i = 0; i < 4; ++i) {
            gload16(bh_src[i] + k0, Bh + ldsB[i]);
            gload16(bl_src[i] + k0, Bl + ldsB[i]);
        }
        #pragma unroll
        for (int j = 0; j < 4; ++j) {
            float xs[8];
            *(float4*)&xs[0] = *(const float4*)(ap + k0 + j * 8);
            *(float4*)&xs[4] = *(const float4*)(ap + k0 + j * 8 + 4);
            ushort oh[8], ol[8];
            #pragma unroll
            for (int i = 0; i < 8; ++i) split2(xs[i], oh[i], ol[i]);
            const int off = swz(srow, skh * 2 + j * 16);
            *(uint4*)(Ah + off) = *(uint4*)oh;
            *(uint4*)(Al + off) = *(uint4*)ol;
        }
        __syncthreads();

        #pragma unroll
        for (int kk = 0; kk < 2; ++kk) {
            short8 ah[4], al[4];
            #pragma unroll
            for (int mi = 0; mi < 4; ++mi) {
                const int off = swz(wm + mi * 16 + lrow, kk * 64 + kg16);
                ah[mi] = *(const short8*)(Ah + off);
                al[mi] = *(const short8*)(Al + off);
            }
            #pragma unroll
            for (int ni = 0; ni < 4; ++ni) {
                const int off = swz(wn + ni * 16 + lrow, kk * 64 + kg16);
                short8 bh = *(const short8*)(Bh + off);
                short8 bl = *(const short8*)(Bl + off);
                #pragma unroll
                for (int mi = 0; mi < 4; ++mi) {
                    acc[mi][ni] = __builtin_amdgcn_mfma_f32_16x16x32_bf16(al[mi], bh, acc[mi][ni], 0, 0, 0);
                    acc[mi][ni] = __builtin_amdgcn_mfma_f32_16x16x32_bf16(ah[mi], bl, acc[mi][ni], 0, 0, 0);
                    acc[mi][ni] = __builtin_amdgcn_mfma_f32_16x16x32_bf16(ah[mi], bh, acc[mi][ni], 0, 0, 0);
                }
            }
        }
        __syncthreads();
    }

    float* C = Cb + z * sC;
    const int r0 = bm + wm + (lane >> 4) * 4;
    const int c0 = bn + wn + (lane & 15);
    #pragma unroll
    for (int ni = 0; ni < 4; ++ni) {
        const int col = c0 + ni * 16;
        #pragma unroll
        for (int mi = 0; mi < 4; ++mi) {
            #pragma unroll
            for (int r = 0; r < 4; ++r) {
                const int row = r0 + mi * 16 + r;
                if (row < M) C[(long long)row * N + col] = acc[mi][ni][r];
            }
        }
    }
}

// ---------------------------------------------------------------------------
// attn GEMM (pre-quant path): A = w_bf bf16 (gload), B = lhsT bf16 (gload).
// ---------------------------------------------------------------------------
__global__ __launch_bounds__(256) void mfma_attn_pre(
    const ushort* __restrict__ Ab, const ushort* __restrict__ Bb,
    float* __restrict__ Cb, int M, int N, int K,
    long long sA, long long sB, long long sC)
{
    extern __shared__ char smem[];
    char* Ah = smem;
    char* Bh = smem + 16384;

    int bx, by, bz; xcd_remap(bx, by, bz);
    const int bm = bx * 128;
    const int bn = by * 128;
    const long long z = bz;

    const ushort* A = Ab + z * sA;
    const ushort* B = Bb + z * sB;

    const int t    = threadIdx.x;
    const int lane = t & 63;
    const int w    = t >> 6;

    const int lr  = lane >> 3;
    const int lc8 = 8 * ((lane & 7) ^ lr);
    const ushort *a_src[4], *b_src[4];
    int ldsO[4];
    #pragma unroll
    for (int i = 0; i < 4; ++i) {
        const int row = w * 32 + i * 8 + lr;
        a_src[i] = A + (long long)min(bm + row, M - 1) * K + lc8;
        b_src[i] = B + (long long)(bn + row) * K + lc8;
        ldsO[i] = w * 4096 + i * 1024;
    }

    const int wm   = (w >> 1) * 64;
    const int wn   = (w & 1) * 64;
    const int lrow = lane & 15;
    const int kg16 = (lane >> 4) * 16;

    f32x4 acc[4][4] = {};

    for (int k0 = 0; k0 < K; k0 += 64) {
        #pragma unroll
        for (int i = 0; i < 4; ++i) {
            gload16(a_src[i] + k0, Ah + ldsO[i]);
            gload16(b_src[i] + k0, Bh + ldsO[i]);
        }
        __syncthreads();

        #pragma unroll
        for (int kk = 0; kk < 2; ++kk) {
            short8 ah[4];
            #pragma unroll
            for (int mi = 0; mi < 4; ++mi)
                ah[mi] = *(const short8*)(Ah + swz(wm + mi * 16 + lrow, kk * 64 + kg16));
            #pragma unroll
            for (int ni = 0; ni < 4; ++ni) {
                short8 bh = *(const short8*)(Bh + swz(wn + ni * 16 + lrow, kk * 64 + kg16));
                #pragma unroll
                for (int mi = 0; mi < 4; ++mi)
                    acc[mi][ni] = __builtin_amdgcn_mfma_f32_16x16x32_bf16(ah[mi], bh, acc[mi][ni], 0, 0, 0);
            }
        }
        __syncthreads();
    }

    float* C = Cb + z * sC;
    const int r0 = bm + wm + (lane >> 4) * 4;
    const int c0 = bn + wn + (lane & 15);
    #pragma unroll
    for (int ni = 0; ni < 4; ++ni) {
        const int col = c0 + ni * 16;
        #pragma unroll
        for (int mi = 0; mi < 4; ++mi) {
            #pragma unroll
            for (int r = 0; r < 4; ++r) {
                const int row = r0 + mi * 16 + r;
                if (row < M) C[(long long)row * N + col] = acc[mi][ni][r];
            }
        }
    }
}

// ---------------------------------------------------------------------------
// attn GEMM (fallback, R4): A = weights f32 reg-staged -> bf16, B gload.
// ---------------------------------------------------------------------------
__global__ __launch_bounds__(256) void mfma_attn(
    const float* __restrict__ Ab, const ushort* __restrict__ Bb,
    float* __restrict__ Cb, int M, int N, int K,
    long long sA, long long sB, long long sC)
{
    extern __shared__ char smem[];
    char* Ah = smem;
    char* Bh = smem + 16384;

    int bx, by, bz; xcd_remap(bx, by, bz);
    const int bm = bx * 128;
    const int bn = by * 128;
    const long long z = bz;

    const float*  A = Ab + z * sA;
    const ushort* B = Bb + z * sB;

    const int t  = threadIdx.x;
    const int lane = t & 63;
    const int w    = t >> 6;

    const int srow = t >> 1;
    const int skh  = (t & 1) * 32;
    const float* ap = A + (long long)min(bm + srow, M - 1) * K + skh;

    const int lr  = lane >> 3;
    const int lc8 = 8 * ((lane & 7) ^ lr);
    const ushort* b_src[4];
    int ldsB[4];
    #pragma unroll
    for (int i = 0; i < 4; ++i) {
        const int row = w * 32 + i * 8 + lr;
        b_src[i] = B + (long long)min(bn + row, N - 1) * K + lc8;
        ldsB[i] = w * 4096 + i * 1024;
    }

    const int wm   = (w >> 1) * 64;
    const int wn   = (w & 1) * 64;
    const int lrow = lane & 15;
    const int kg16 = (lane >> 4) * 16;

    f32x4 acc[4][4] = {};

    for (int k0 = 0; k0 < K; k0 += 64) {
        #pragma unroll
        for (int i = 0; i < 4; ++i)
            gload16(b_src[i] + k0, Bh + ldsB[i]);
        #pragma unroll
        for (int j = 0; j < 4; ++j) {
            float xs[8];
            *(float4*)&xs[0] = *(const float4*)(ap + k0 + j * 8);
            *(float4*)&xs[4] = *(const float4*)(ap + k0 + j * 8 + 4);
            ushort o[8];
            #pragma unroll
            for (int i = 0; i < 8; ++i) o[i] = f2bf(xs[i]);
            *(uint4*)(Ah + swz(srow, skh * 2 + j * 16)) = *(uint4*)o;
        }
        __syncthreads();

        #pragma unroll
        for (int kk = 0; kk < 2; ++kk) {
            short8 ah[4];
            #pragma unroll
            for (int mi = 0; mi < 4; ++mi)
                ah[mi] = *(const short8*)(Ah + swz(wm + mi * 16 + lrow, kk * 64 + kg16));
            #pragma unroll
            for (int ni = 0; ni < 4; ++ni) {
                short8 bh = *(const short8*)(Bh + swz(wn + ni * 16 + lrow, kk * 64 + kg16));
                #pragma unroll
                for (int mi = 0; mi < 4; ++mi)
                    acc[mi][ni] = __builtin_amdgcn_mfma_f32_16x16x32_bf16(ah[mi], bh, acc[mi][ni], 0, 0, 0);
            }
        }
        __syncthreads();
    }

    float* C = Cb + z * sC;
    const int r0 = bm + wm + (lane >> 4) * 4;
    const int c0 = bn + wn + (lane & 15);
    #pragma unroll
    for (int ni = 0; ni < 4; ++ni) {
        const int col = c0 + ni * 16;
        #pragma unroll
        for (int mi = 0; mi < 4; ++mi) {
            #pragma unroll
            for (int r = 0; r < 4; ++r) {
                const int row = r0 + mi * 16 + r;
                if (row < M) C[(long long)row * N + col] = acc[mi][ni][r];
            }
        }
    }
}

// ---------------------------------------------------------------------------
// lhs [B,S,D] f32  ->  lhsT [B,D,S] bf16
// ---------------------------------------------------------------------------
__global__ __launch_bounds__(256) void transpose_bf16_kernel(
    const float* __restrict__ in, ushort* __restrict__ out, int S, int D)
{
    __shared__ float tile[32][33];
    const int b = blockIdx.z;
    const int s0 = blockIdx.x * 32, d0 = blockIdx.y * 32;
    const int tx = threadIdx.x & 31, ty = threadIdx.x >> 5;
    const float* ip = in + (long long)b * S * D;
    #pragma unroll
    for (int i = 0; i < 32; i += 8)
        tile[ty + i][tx] = ip[(long long)(s0 + ty + i) * D + d0 + tx];
    __syncthreads();
    ushort* op = out + (long long)b * S * D;
    #pragma unroll
    for (int i = 0; i < 32; i += 8)
        op[(long long)(d0 + ty + i) * S + s0 + tx] = f2bf(tile[tx][ty + i]);
}

// ---------------------------------------------------------------------------
// Softmax over L of scores [B,L,S] (in place), 3 passes.
// ---------------------------------------------------------------------------
__global__ __launch_bounds__(256) void softmax_part_kernel(
    const float* __restrict__ scores, float* __restrict__ pm,
    float* __restrict__ ps, int L, int S, int chlen)
{
    int s = blockIdx.x * 256 + threadIdx.x;
    int c = blockIdx.y;
    int b = blockIdx.z;
    int l0 = c * chlen;
    int l1 = min(L, l0 + chlen);
    const float* p = scores + (long long)b * L * S + s;
    float m = -INFINITY, sum = 0.f;
    for (int l = l0; l < l1; ++l) {
        float x = p[(long long)l * S];
        float nm = fmaxf(m, x);
        sum = sum * __expf(m - nm) + __expf(x - nm);
        m = nm;
    }
    int idx = (b * SM_CH + c) * S + s;
    pm[idx] = m;
    ps[idx] = sum;
}

__global__ __launch_bounds__(256) void softmax_merge_kernel(
    const float* __restrict__ pm, const float* __restrict__ ps,
    float* __restrict__ fm, float* __restrict__ fsinv, int S)
{
    int s = blockIdx.x * 256 + threadIdx.x;
    int b = blockIdx.y;
    float m = -INFINITY;
    #pragma unroll
    for (int c = 0; c < SM_CH; ++c)
        m = fmaxf(m, pm[(b * SM_CH + c) * S + s]);
    float sum = 0.f;
    #pragma unroll
    for (int c = 0; c < SM_CH; ++c)
        sum += ps[(b * SM_CH + c) * S + s] * __expf(pm[(b * SM_CH + c) * S + s] - m);
    fm[b * S + s] = m;
    fsinv[b * S + s] = 1.f / sum;
}

__global__ __launch_bounds__(256) void softmax_write_kernel(
    float* __restrict__ scores, const float* __restrict__ fm,
    const float* __restrict__ fsinv, int L, int S, int chlen,
    ushort* __restrict__ wbf)
{
    int s = blockIdx.x * 256 + threadIdx.x;
    int c = blockIdx.y;
    int b = blockIdx.z;
    float m   = fm[b * S + s];
    float inv = fsinv[b * S + s];
    float* p = scores + (long long)b * L * S + s;
    ushort* q = wbf ? (wbf + (long long)b * L * S + s) : nullptr;
    int l0 = c * chlen;
    int l1 = min(L, l0 + chlen);
    for (int l = l0; l < l1; ++l) {
        float x = p[(long long)l * S];
        float v = __expf(x - m) * inv;
        p[(long long)l * S] = v;
        if (q) q[(long long)l * S] = f2bf(v);
    }
}

extern "C" void kernel_launch(void* const* d_in, const int* in_sizes, int n_in,
                              void* d_out, int out_size, void* d_ws, size_t ws_size,
                              hipStream_t stream)
{
    const int Bn = 8, S = 512, D = 768, E = 768, L = 4000;
    const float* lhs   = (const float*)d_in[0];   // [B,S,D]
    const float* label = (const float*)d_in[1];   // [L,E]
    const float* W     = (const float*)d_in[2];   // [E,D]
    const float* bias  = (const float*)d_in[3];   // [E]

    float* weights = (float*)d_out;                          // [B,L,S]
    float* attn    = (float*)d_out + (long long)Bn * L * S;  // [B,L,D]

    const long long nLE  = (long long)L * E;        // 3,072,000
    const long long nBSE = (long long)Bn * S * E;   // 3,145,728
    const long long nBDS = (long long)Bn * D * S;   // 3,145,728
    const long long nBLS = (long long)Bn * L * S;   // 16,384,000

    // Big-ws path layout (~65.0 MB); fallback path (~19.5 MB).
    const size_t need_big = (size_t)(2 * nLE + 2 * nBSE + nBDS + nBLS) * 2
                          + (size_t)(2 * Bn * SM_CH * S + 2 * Bn * S) * 4;
    const bool big = ws_size >= need_big;

    ushort* labelH = nullptr; ushort* labelL = nullptr; ushort* wbf = nullptr;
    ushort* projH; ushort* projL; ushort* lhsT; float* pm;

    if (big) {
        labelH = (ushort*)d_ws;
        labelL = labelH + nLE;
        projH  = labelL + nLE;
        projL  = projH + nBSE;
        lhsT   = projL + nBSE;
        wbf    = lhsT + nBDS;
        pm     = (float*)(wbf + nBLS);
    } else {
        projH  = (ushort*)d_ws;
        projL  = projH + nBSE;
        lhsT   = projL + nBSE;
        pm     = (float*)(lhsT + nBDS);
    }
    float* ps    = pm + Bn * SM_CH * S;
    float* fm    = ps + Bn * SM_CH * S;
    float* fsinv = fm + Bn * S;

    const int chlen = (L + SM_CH - 1) / SM_CH;  // 125

    // 0) lhsT = transpose(lhs) bf16; label planes (big path)
    transpose_bf16_kernel<<<dim3(S / 32, D / 32, Bn), 256, 0, stream>>>(
        lhs, lhsT, S, D);
    if (big)
        split_planes_kernel<<<(int)(nLE / 4 + 255) / 256, 256, 0, stream>>>(
            label, labelH, labelL, nLE / 4);

    // 1) projH/L = split(tanh(lhs @ W^T + bias)): M=4096, N=E, K=D
    mfma_proj<<<dim3((Bn * S) / 128, E / 128, 1), 256, 65536, stream>>>(
        lhs, W, projH, projL, bias, Bn * S, E, D);

    // 2) scores[b] = label @ proj[b]^T: M=L, N=S, K=E (3-term)
    if (big)
        mfma_scores_pre<<<dim3((L + 127) / 128, S / 128, Bn), 256, 65536, stream>>>(
            labelH, labelL, projH, projL, weights, L, S, E,
            (long long)S * E, (long long)L * S);
    else
        mfma_scores<<<dim3((L + 127) / 128, S / 128, Bn), 256, 65536, stream>>>(
            label, projH, projL, weights, L, S, E,
            (long long)S * E, (long long)L * S);

    // 3) softmax over L, in place (+ bf16 copy on big path)
    softmax_part_kernel<<<dim3(S / 256, SM_CH, Bn), 256, 0, stream>>>(
        weights, pm, ps, L, S, chlen);
    softmax_merge_kernel<<<dim3(S / 256, Bn), 256, 0, stream>>>(
        pm, ps, fm, fsinv, S);
    softmax_write_kernel<<<dim3(S / 256, SM_CH, Bn), 256, 0, stream>>>(
        weights, fm, fsinv, L, S, chlen, wbf);

    // 4) attn[b] = weights[b] @ lhsT[b]^T: M=L, N=D, K=S (1-term)
    if (big)
        mfma_attn_pre<<<dim3((L + 127) / 128, D / 128, Bn), 256, 32768, stream>>>(
            wbf, lhsT, attn, L, D, S,
            (long long)L * S, (long long)D * S, (long long)L * D);
    else
        mfma_attn<<<dim3((L + 127) / 128, D / 128, Bn), 256, 32768, stream>>>(
            weights, lhsT, attn, L, D, S,
            (long long)L * S, (long long)D * S, (long long)L * D);
}

// Round 6
// 265.346 us; speedup vs baseline: 3.2828x; 1.0782x over previous
//
#include <hip/hip_runtime.h>
#include <hip/hip_bf16.h>
#include <cmath>

typedef __attribute__((ext_vector_type(8))) short short8;
typedef __attribute__((ext_vector_type(4))) float f32x4;

#define SM_CH 32   // = number of 128-row L-chunks: 4000/128 -> 32 blocks

__device__ inline ushort f2bf(float x) {
    union { float f; unsigned u; } v; v.f = x;
    unsigned r = v.u + 0x7FFF + ((v.u >> 16) & 1);   // RNE
    return (ushort)(r >> 16);
}

// Truncation split: x ~= hi + lo
__device__ inline void split2(float x, ushort& hi, ushort& lo) {
    union { float f; unsigned u; } v; v.f = x;
    hi = (ushort)(v.u >> 16);
    union { float f; unsigned u; } h; h.u = v.u & 0xFFFF0000u;
    union { float f; unsigned u; } d; d.f = x - h.f;
    lo = (ushort)(d.u >> 16);
}

// byte offset within one [rows x 128B] LDS plane, XOR-swizzled.
__device__ inline int swz(int row, int byte_in_row) {
    return row * 128 + (byte_in_row ^ ((row & 7) << 4));
}

// async global->LDS, 16B per lane. lds base wave-uniform; HW adds lane*16.
__device__ inline void gload16(const void* g, void* lds) {
    __builtin_amdgcn_global_load_lds(
        (const __attribute__((address_space(1))) unsigned int*)g,
        (__attribute__((address_space(3))) unsigned int*)lds, 16, 0, 0);
}

// T1: bijective XCD-aware block remap (requires nwg % 8 == 0).
__device__ inline void xcd_remap(int& bx, int& by, int& bz) {
    unsigned nx = gridDim.x, ny = gridDim.y;
    unsigned nwg = nx * ny * gridDim.z;
    unsigned id = blockIdx.x + nx * (blockIdx.y + ny * blockIdx.z);
    unsigned q = nwg >> 3;
    unsigned s = (id & 7) * q + (id >> 3);
    bx = s % nx; unsigned r = s / nx;
    by = r % ny; bz = r / ny;
}

// ---------------------------------------------------------------------------
// split f32 array -> hi/lo bf16 planes (one-shot, for label)
// ---------------------------------------------------------------------------
__global__ __launch_bounds__(256) void split_planes_kernel(
    const float* __restrict__ in, ushort* __restrict__ H,
    ushort* __restrict__ L, long long n4)
{
    long long i = (long long)blockIdx.x * 256 + threadIdx.x;
    if (i >= n4) return;
    float4 v = *(const float4*)(in + i * 4);
    ushort h[4], l[4];
    split2(v.x, h[0], l[0]); split2(v.y, h[1], l[1]);
    split2(v.z, h[2], l[2]); split2(v.w, h[3], l[3]);
    *(ushort4*)(H + i * 4) = *(ushort4*)h;
    *(ushort4*)(L + i * 4) = *(ushort4*)l;
}

// ---------------------------------------------------------------------------
// proj GEMM: projH/projL = split2(tanh(lhs @ W^T + bias)); 3-term split.
// ---------------------------------------------------------------------------
__global__ __launch_bounds__(256) void mfma_proj(
    const float* __restrict__ Ab, const float* __restrict__ Bb,
    ushort* __restrict__ CH, ushort* __restrict__ CL,
    const float* __restrict__ bias, int M, int N, int K)
{
    extern __shared__ char smem[];
    char* Ah = smem;
    char* Al = smem + 16384;
    char* Bh = smem + 32768;
    char* Bl = smem + 49152;

    int bx, by, bz; xcd_remap(bx, by, bz);
    const int bm = bx * 128;
    const int bn = by * 128;

    const int t  = threadIdx.x;
    const int srow = t >> 1;
    const int skh  = (t & 1) * 32;
    const float* ap = Ab + (long long)min(bm + srow, M - 1) * K + skh;
    const float* bp = Bb + (long long)min(bn + srow, N - 1) * K + skh;

    const int lane = t & 63;
    const int w    = t >> 6;
    const int wm   = (w >> 1) * 64;
    const int wn   = (w & 1) * 64;
    const int lrow = lane & 15;
    const int kg16 = (lane >> 4) * 16;

    f32x4 acc[4][4] = {};

    for (int k0 = 0; k0 < K; k0 += 64) {
        #pragma unroll
        for (int j = 0; j < 4; ++j) {
            float xs[8];
            *(float4*)&xs[0] = *(const float4*)(ap + k0 + j * 8);
            *(float4*)&xs[4] = *(const float4*)(ap + k0 + j * 8 + 4);
            ushort oh[8], ol[8];
            #pragma unroll
            for (int i = 0; i < 8; ++i) split2(xs[i], oh[i], ol[i]);
            const int off = swz(srow, skh * 2 + j * 16);
            *(uint4*)(Ah + off) = *(uint4*)oh;
            *(uint4*)(Al + off) = *(uint4*)ol;
        }
        #pragma unroll
        for (int j = 0; j < 4; ++j) {
            float xs[8];
            *(float4*)&xs[0] = *(const float4*)(bp + k0 + j * 8);
            *(float4*)&xs[4] = *(const float4*)(bp + k0 + j * 8 + 4);
            ushort oh[8], ol[8];
            #pragma unroll
            for (int i = 0; i < 8; ++i) split2(xs[i], oh[i], ol[i]);
            const int off = swz(srow, skh * 2 + j * 16);
            *(uint4*)(Bh + off) = *(uint4*)oh;
            *(uint4*)(Bl + off) = *(uint4*)ol;
        }
        __syncthreads();

        #pragma unroll
        for (int kk = 0; kk < 2; ++kk) {
            short8 ah[4], al[4];
            #pragma unroll
            for (int mi = 0; mi < 4; ++mi) {
                const int off = swz(wm + mi * 16 + lrow, kk * 64 + kg16);
                ah[mi] = *(const short8*)(Ah + off);
                al[mi] = *(const short8*)(Al + off);
            }
            #pragma unroll
            for (int ni = 0; ni < 4; ++ni) {
                const int off = swz(wn + ni * 16 + lrow, kk * 64 + kg16);
                short8 bh = *(const short8*)(Bh + off);
                short8 bl = *(const short8*)(Bl + off);
                #pragma unroll
                for (int mi = 0; mi < 4; ++mi) {
                    acc[mi][ni] = __builtin_amdgcn_mfma_f32_16x16x32_bf16(al[mi], bh, acc[mi][ni], 0, 0, 0);
                    acc[mi][ni] = __builtin_amdgcn_mfma_f32_16x16x32_bf16(ah[mi], bl, acc[mi][ni], 0, 0, 0);
                    acc[mi][ni] = __builtin_amdgcn_mfma_f32_16x16x32_bf16(ah[mi], bh, acc[mi][ni], 0, 0, 0);
                }
            }
        }
        __syncthreads();
    }

    const int r0 = bm + wm + (lane >> 4) * 4;
    const int c0 = bn + wn + (lane & 15);
    #pragma unroll
    for (int ni = 0; ni < 4; ++ni) {
        const int col = c0 + ni * 16;
        const float bv = bias[col];
        #pragma unroll
        for (int mi = 0; mi < 4; ++mi) {
            #pragma unroll
            for (int r = 0; r < 4; ++r) {
                const int row = r0 + mi * 16 + r;
                if (row < M) {
                    float x = tanhf(acc[mi][ni][r] + bv);
                    ushort h, l;
                    split2(x, h, l);
                    CH[(long long)row * N + col] = h;
                    CL[(long long)row * N + col] = l;
                }
            }
        }
    }
}

// ---------------------------------------------------------------------------
// scores GEMM: weights[b] = labelHL @ projHL[b]^T, 3-term split, all planes
// via global_load_lds. Epilogue additionally reduces per-column (max, sum)
// over this block's 128 L-rows into pm/ps[b, bx, s] (chunk = L-block).
// ---------------------------------------------------------------------------
__global__ __launch_bounds__(256) void mfma_scores_pre(
    const ushort* __restrict__ AHb, const ushort* __restrict__ ALb,
    const ushort* __restrict__ BHb, const ushort* __restrict__ BLb,
    float* __restrict__ Cb, float* __restrict__ pmo, float* __restrict__ pso,
    int M, int N, int K, long long sB, long long sC)
{
    extern __shared__ char smem[];
    char* Ah = smem;
    char* Al = smem + 16384;
    char* Bh = smem + 32768;
    char* Bl = smem + 49152;

    int bx, by, bz; xcd_remap(bx, by, bz);
    const int bm = bx * 128;
    const int bn = by * 128;
    const long long z = bz;

    const ushort* BH = BHb + z * sB;
    const ushort* BL = BLb + z * sB;

    const int t    = threadIdx.x;
    const int lane = t & 63;
    const int w    = t >> 6;

    const int lr  = lane >> 3;
    const int lc8 = 8 * ((lane & 7) ^ lr);   // inverse-swizzled src col
    const ushort *ah_src[4], *al_src[4], *bh_src[4], *bl_src[4];
    int ldsO[4];
    #pragma unroll
    for (int i = 0; i < 4; ++i) {
        const int row = w * 32 + i * 8 + lr;
        ah_src[i] = AHb + (long long)min(bm + row, M - 1) * K + lc8;
        al_src[i] = ALb + (long long)min(bm + row, M - 1) * K + lc8;
        bh_src[i] = BH  + (long long)(bn + row) * K + lc8;
        bl_src[i] = BL  + (long long)(bn + row) * K + lc8;
        ldsO[i] = w * 4096 + i * 1024;
    }

    const int wm   = (w >> 1) * 64;
    const int wn   = (w & 1) * 64;
    const int lrow = lane & 15;
    const int kg16 = (lane >> 4) * 16;

    f32x4 acc[4][4] = {};

    for (int k0 = 0; k0 < K; k0 += 64) {
        #pragma unroll
        for (int i = 0; i < 4; ++i) {
            gload16(ah_src[i] + k0, Ah + ldsO[i]);
            gload16(al_src[i] + k0, Al + ldsO[i]);
            gload16(bh_src[i] + k0, Bh + ldsO[i]);
            gload16(bl_src[i] + k0, Bl + ldsO[i]);
        }
        __syncthreads();

        #pragma unroll
        for (int kk = 0; kk < 2; ++kk) {
            short8 ah[4], al[4];
            #pragma unroll
            for (int mi = 0; mi < 4; ++mi) {
                const int off = swz(wm + mi * 16 + lrow, kk * 64 + kg16);
                ah[mi] = *(const short8*)(Ah + off);
                al[mi] = *(const short8*)(Al + off);
            }
            #pragma unroll
            for (int ni = 0; ni < 4; ++ni) {
                const int off = swz(wn + ni * 16 + lrow, kk * 64 + kg16);
                short8 bh = *(const short8*)(Bh + off);
                short8 bl = *(const short8*)(Bl + off);
                #pragma unroll
                for (int mi = 0; mi < 4; ++mi) {
                    acc[mi][ni] = __builtin_amdgcn_mfma_f32_16x16x32_bf16(al[mi], bh, acc[mi][ni], 0, 0, 0);
                    acc[mi][ni] = __builtin_amdgcn_mfma_f32_16x16x32_bf16(ah[mi], bl, acc[mi][ni], 0, 0, 0);
                    acc[mi][ni] = __builtin_amdgcn_mfma_f32_16x16x32_bf16(ah[mi], bh, acc[mi][ni], 0, 0, 0);
                }
            }
        }
        __syncthreads();
    }

    // ---- C write ----
    float* C = Cb + z * sC;
    const int r0 = bm + wm + (lane >> 4) * 4;
    const int c0 = bn + wn + (lane & 15);
    #pragma unroll
    for (int ni = 0; ni < 4; ++ni) {
        const int col = c0 + ni * 16;
        #pragma unroll
        for (int mi = 0; mi < 4; ++mi) {
            #pragma unroll
            for (int r = 0; r < 4; ++r) {
                const int row = r0 + mi * 16 + r;
                if (row < M) C[(long long)row * N + col] = acc[mi][ni][r];
            }
        }
    }

    // ---- fused per-column partial softmax stats over the block's 128 rows ----
    // red[col 0..127][slot 0..7]; safe to alias smem after final barrier above.
    float* red = (float*)smem;
    const int slot = ((w >> 1) << 2) | (lane >> 4);
    const int colb = wn + (lane & 15);

    float lm[4];
    #pragma unroll
    for (int ni = 0; ni < 4; ++ni) {
        float v = -INFINITY;
        #pragma unroll
        for (int mi = 0; mi < 4; ++mi)
            #pragma unroll
            for (int r = 0; r < 4; ++r)
                if (r0 + mi * 16 + r < M) v = fmaxf(v, acc[mi][ni][r]);
        lm[ni] = v;
    }
    #pragma unroll
    for (int ni = 0; ni < 4; ++ni)
        red[(colb + ni * 16) * 8 + slot] = lm[ni];
    __syncthreads();
    float cm[4];
    #pragma unroll
    for (int ni = 0; ni < 4; ++ni) {
        float v = -INFINITY;
        #pragma unroll
        for (int s8 = 0; s8 < 8; ++s8)
            v = fmaxf(v, red[(colb + ni * 16) * 8 + s8]);
        cm[ni] = v;
    }
    __syncthreads();
    float ls[4];
    #pragma unroll
    for (int ni = 0; ni < 4; ++ni) {
        float sum = 0.f;
        #pragma unroll
        for (int mi = 0; mi < 4; ++mi)
            #pragma unroll
            for (int r = 0; r < 4; ++r)
                if (r0 + mi * 16 + r < M) sum += __expf(acc[mi][ni][r] - cm[ni]);
        ls[ni] = sum;
    }
    #pragma unroll
    for (int ni = 0; ni < 4; ++ni)
        red[(colb + ni * 16) * 8 + slot] = ls[ni];
    __syncthreads();
    if (slot == 0) {
        #pragma unroll
        for (int ni = 0; ni < 4; ++ni) {
            float sum = 0.f;
            #pragma unroll
            for (int s8 = 0; s8 < 8; ++s8)
                sum += red[(colb + ni * 16) * 8 + s8];
            const int col = bn + colb + ni * 16;
            pmo[(z * SM_CH + bx) * N + col] = cm[ni];
            pso[(z * SM_CH + bx) * N + col] = sum;
        }
    }
}

// ---------------------------------------------------------------------------
// attn GEMM: attn[b] = w_bf[b] @ lhsT[b]^T, 1-term bf16, 128x256 tile.
// A-tile (wbf) shared across a 256-wide D stripe -> halves wbf re-fetch.
// ---------------------------------------------------------------------------
__global__ __launch_bounds__(256) void mfma_attn2(
    const ushort* __restrict__ Ab, const ushort* __restrict__ Bb,
    float* __restrict__ Cb, int M, int N, int K,
    long long sA, long long sB, long long sC)
{
    extern __shared__ char smem[];
    char* Ah = smem;             // 128 x 128B = 16 KB
    char* Bh = smem + 16384;     // 256 x 128B = 32 KB

    int bx, by, bz; xcd_remap(bx, by, bz);
    const int bm = bx * 128;
    const int bn = by * 256;
    const long long z = bz;

    const ushort* A = Ab + z * sA;
    const ushort* B = Bb + z * sB;

    const int t    = threadIdx.x;
    const int lane = t & 63;
    const int w    = t >> 6;

    const int lr  = lane >> 3;
    const int lc8 = 8 * ((lane & 7) ^ lr);
    const ushort* a_src[4];
    int ldsA[4];
    #pragma unroll
    for (int i = 0; i < 4; ++i) {
        const int row = w * 32 + i * 8 + lr;
        a_src[i] = A + (long long)min(bm + row, M - 1) * K + lc8;
        ldsA[i] = w * 4096 + i * 1024;
    }
    const ushort* b_src[8];
    int ldsB[8];
    #pragma unroll
    for (int i = 0; i < 8; ++i) {
        const int row = w * 64 + i * 8 + lr;
        b_src[i] = B + (long long)(bn + row) * K + lc8;
        ldsB[i] = w * 8192 + i * 1024;
    }

    const int wm   = (w >> 1) * 64;
    const int wn   = (w & 1) * 128;
    const int lrow = lane & 15;
    const int kg16 = (lane >> 4) * 16;

    f32x4 acc[4][8] = {};

    for (int k0 = 0; k0 < K; k0 += 64) {
        #pragma unroll
        for (int i = 0; i < 4; ++i)
            gload16(a_src[i] + k0, Ah + ldsA[i]);
        #pragma unroll
        for (int i = 0; i < 8; ++i)
            gload16(b_src[i] + k0, Bh + ldsB[i]);
        __syncthreads();

        #pragma unroll
        for (int kk = 0; kk < 2; ++kk) {
            short8 ah[4];
            #pragma unroll
            for (int mi = 0; mi < 4; ++mi)
                ah[mi] = *(const short8*)(Ah + swz(wm + mi * 16 + lrow, kk * 64 + kg16));
            #pragma unroll
            for (int ni = 0; ni < 8; ++ni) {
                short8 bh = *(const short8*)(Bh + swz(wn + ni * 16 + lrow, kk * 64 + kg16));
                #pragma unroll
                for (int mi = 0; mi < 4; ++mi)
                    acc[mi][ni] = __builtin_amdgcn_mfma_f32_16x16x32_bf16(ah[mi], bh, acc[mi][ni], 0, 0, 0);
            }
        }
        __syncthreads();
    }

    float* C = Cb + z * sC;
    const int r0 = bm + wm + (lane >> 4) * 4;
    const int c0 = bn + wn + (lane & 15);
    #pragma unroll
    for (int ni = 0; ni < 8; ++ni) {
        const int col = c0 + ni * 16;
        #pragma unroll
        for (int mi = 0; mi < 4; ++mi) {
            #pragma unroll
            for (int r = 0; r < 4; ++r) {
                const int row = r0 + mi * 16 + r;
                if (row < M) C[(long long)row * N + col] = acc[mi][ni][r];
            }
        }
    }
}

// ---------------------------------------------------------------------------
// lhs [B,S,D] f32  ->  lhsT [B,D,S] bf16
// ---------------------------------------------------------------------------
__global__ __launch_bounds__(256) void transpose_bf16_kernel(
    const float* __restrict__ in, ushort* __restrict__ out, int S, int D)
{
    __shared__ float tile[32][33];
    const int b = blockIdx.z;
    const int s0 = blockIdx.x * 32, d0 = blockIdx.y * 32;
    const int tx = threadIdx.x & 31, ty = threadIdx.x >> 5;
    const float* ip = in + (long long)b * S * D;
    #pragma unroll
    for (int i = 0; i < 32; i += 8)
        tile[ty + i][tx] = ip[(long long)(s0 + ty + i) * D + d0 + tx];
    __syncthreads();
    ushort* op = out + (long long)b * S * D;
    #pragma unroll
    for (int i = 0; i < 32; i += 8)
        op[(long long)(d0 + ty + i) * S + s0 + tx] = f2bf(tile[tx][ty + i]);
}

// ---------------------------------------------------------------------------
// Softmax merge + write (chunk stats produced by scores epilogue).
// ---------------------------------------------------------------------------
__global__ __launch_bounds__(256) void softmax_merge_kernel(
    const float* __restrict__ pm, const float* __restrict__ ps,
    float* __restrict__ fm, float* __restrict__ fsinv, int S)
{
    int s = blockIdx.x * 256 + threadIdx.x;
    int b = blockIdx.y;
    float m = -INFINITY;
    #pragma unroll
    for (int c = 0; c < SM_CH; ++c)
        m = fmaxf(m, pm[(b * SM_CH + c) * S + s]);
    float sum = 0.f;
    #pragma unroll
    for (int c = 0; c < SM_CH; ++c)
        sum += ps[(b * SM_CH + c) * S + s] * __expf(pm[(b * SM_CH + c) * S + s] - m);
    fm[b * S + s] = m;
    fsinv[b * S + s] = 1.f / sum;
}

__global__ __launch_bounds__(256) void softmax_write_kernel(
    float* __restrict__ scores, const float* __restrict__ fm,
    const float* __restrict__ fsinv, int L, int S, int chlen,
    ushort* __restrict__ wbf)
{
    int s = blockIdx.x * 256 + threadIdx.x;
    int c = blockIdx.y;
    int b = blockIdx.z;
    float m   = fm[b * S + s];
    float inv = fsinv[b * S + s];
    float* p = scores + (long long)b * L * S + s;
    ushort* q = wbf + (long long)b * L * S + s;
    int l0 = c * chlen;
    int l1 = min(L, l0 + chlen);
    for (int l = l0; l < l1; ++l) {
        float x = p[(long long)l * S];
        float v = __expf(x - m) * inv;
        p[(long long)l * S] = v;
        q[(long long)l * S] = f2bf(v);
    }
}

extern "C" void kernel_launch(void* const* d_in, const int* in_sizes, int n_in,
                              void* d_out, int out_size, void* d_ws, size_t ws_size,
                              hipStream_t stream)
{
    const int Bn = 8, S = 512, D = 768, E = 768, L = 4000;
    const float* lhs   = (const float*)d_in[0];   // [B,S,D]
    const float* label = (const float*)d_in[1];   // [L,E]
    const float* W     = (const float*)d_in[2];   // [E,D]
    const float* bias  = (const float*)d_in[3];   // [E]

    float* weights = (float*)d_out;                          // [B,L,S]
    float* attn    = (float*)d_out + (long long)Bn * L * S;  // [B,L,D]

    const long long nLE  = (long long)L * E;        // 3,072,000
    const long long nBSE = (long long)Bn * S * E;   // 3,145,728
    const long long nBDS = (long long)Bn * D * S;   // 3,145,728
    const long long nBLS = (long long)Bn * L * S;   // 16,384,000

    ushort* labelH = (ushort*)d_ws;
    ushort* labelL = labelH + nLE;
    ushort* projH  = labelL + nLE;
    ushort* projL  = projH + nBSE;
    ushort* lhsT   = projL + nBSE;
    ushort* wbf    = lhsT + nBDS;
    float*  pm     = (float*)(wbf + nBLS);
    float*  ps     = pm + Bn * SM_CH * S;
    float*  fm     = ps + Bn * SM_CH * S;
    float*  fsinv  = fm + Bn * S;

    const int chlen = (L + SM_CH - 1) / SM_CH;  // 125 (write pass chunking)

    // 0) lhsT = transpose(lhs) bf16; label hi/lo planes
    transpose_bf16_kernel<<<dim3(S / 32, D / 32, Bn), 256, 0, stream>>>(
        lhs, lhsT, S, D);
    split_planes_kernel<<<(int)(nLE / 4 + 255) / 256, 256, 0, stream>>>(
        label, labelH, labelL, nLE / 4);

    // 1) projH/L = split(tanh(lhs @ W^T + bias)): M=4096, N=E, K=D
    mfma_proj<<<dim3((Bn * S) / 128, E / 128, 1), 256, 65536, stream>>>(
        lhs, W, projH, projL, bias, Bn * S, E, D);

    // 2) scores[b] = label @ proj[b]^T + fused per-chunk (max,sum) partials
    mfma_scores_pre<<<dim3((L + 127) / 128, S / 128, Bn), 256, 65536, stream>>>(
        labelH, labelL, projH, projL, weights, pm, ps, L, S, E,
        (long long)S * E, (long long)L * S);

    // 3) softmax merge + write (in place, + bf16 copy)
    softmax_merge_kernel<<<dim3(S / 256, Bn), 256, 0, stream>>>(
        pm, ps, fm, fsinv, S);
    softmax_write_kernel<<<dim3(S / 256, SM_CH, Bn), 256, 0, stream>>>(
        weights, fm, fsinv, L, S, chlen, wbf);

    // 4) attn[b] = wbf[b] @ lhsT[b]^T: M=L, N=D, K=S (1-term, 128x256)
    mfma_attn2<<<dim3((L + 127) / 128, D / 256, Bn), 256, 49152, stream>>>(
        wbf, lhsT, attn, L, D, S,
        (long long)L * S, (long long)D * S, (long long)L * D);
}

// Round 8
// 250.801 us; speedup vs baseline: 3.4732x; 1.0580x over previous
//
#include <hip/hip_runtime.h>
#include <hip/hip_bf16.h>
#include <cmath>

typedef __attribute__((ext_vector_type(8))) short short8;
typedef __attribute__((ext_vector_type(4))) float f32x4;

#define SM_CH 16   // scores stats chunks: 4000 rows / 256-row blocks -> 16
#define WCH   32   // softmax write-pass chunking

__device__ inline ushort f2bf(float x) {
    union { float f; unsigned u; } v; v.f = x;
    unsigned r = v.u + 0x7FFF + ((v.u >> 16) & 1);   // RNE
    return (ushort)(r >> 16);
}

__device__ inline void split2(float x, ushort& hi, ushort& lo) {
    union { float f; unsigned u; } v; v.f = x;
    hi = (ushort)(v.u >> 16);
    union { float f; unsigned u; } h; h.u = v.u & 0xFFFF0000u;
    union { float f; unsigned u; } d; d.f = x - h.f;
    lo = (ushort)(d.u >> 16);
}

// byte offset within one [rows x 128B] LDS plane, XOR-swizzled (T2).
__device__ inline int swz(int row, int byte_in_row) {
    return row * 128 + (byte_in_row ^ ((row & 7) << 4));
}

// async global->LDS, 16B/lane; lds base wave-uniform, HW adds lane*16.
__device__ inline void gload16(const void* g, void* lds) {
    __builtin_amdgcn_global_load_lds(
        (const __attribute__((address_space(1))) unsigned int*)g,
        (__attribute__((address_space(3))) unsigned int*)lds, 16, 0, 0);
}

// T1: bijective XCD-aware block remap (requires nwg % 8 == 0).
__device__ inline void xcd_remap(int& bx, int& by, int& bz) {
    unsigned nx = gridDim.x, ny = gridDim.y;
    unsigned nwg = nx * ny * gridDim.z;
    unsigned id = blockIdx.x + nx * (blockIdx.y + ny * blockIdx.z);
    unsigned q = nwg >> 3;
    unsigned s = (id & 7) * q + (id >> 3);
    bx = s % nx; unsigned r = s / nx;
    by = r % ny; bz = r / ny;
}

// stage one bf16 plane tile: ROWS x 64 k-elems into [ROWS x 128B] LDS plane.
// Linear LDS dest + inverse-swizzled global source (both-sides rule).
template<int ROWS, int KS>
__device__ inline void stage_plane(const ushort* __restrict__ src,
                                   char* plane, int t, int rbase, int rmax)
{
    #pragma unroll
    for (int s = 0; s < ROWS / 64; ++s) {
        const int row = s * 64 + (t >> 3);
        const int col = (((t & 7) * 16) ^ ((row & 7) << 4)) >> 1;  // elems
        const int gr  = min(rbase + row, rmax);
        gload16(src + (long long)gr * KS + col,
                plane + s * 8192 + (t >> 6) * 1024);
    }
}

// ---------------------------------------------------------------------------
// 8-wave, BN=256, BK=64, double-buffered, counted-vmcnt GEMM.
// C[m,n] = sum_k A[m,k]*B[n,k] over pseudo-K = NT*64.
// SPLIT3: A-planes [AH|AH|AL], B-planes [BH|BL|BH] per 12-tile segment
//         (3-term split-bf16 product via K-concatenation).
// STATS : fused per-column (max, sum) partials over the block's BM rows.
// sA/sB : per-batch element strides for A and B (0 if batch-shared).
// ---------------------------------------------------------------------------
template<bool SPLIT3, int BM, int MREP, bool STATS, int NT, int KS, int VMN>
__global__ __launch_bounds__(512, 2) void mfma8(
    const ushort* __restrict__ AH, const ushort* __restrict__ AL,
    const ushort* __restrict__ BH, const ushort* __restrict__ BL,
    float* __restrict__ Cb, float* __restrict__ pmo, float* __restrict__ pso,
    int M, int N, long long sA, long long sB, long long sC)
{
    extern __shared__ char smem[];
    constexpr int ABYTES = BM * 128;          // one A buffer
    // layout: [A0 | A1 | B0 | B1]

    int bx, by, bz; xcd_remap(bx, by, bz);
    const int bm = bx * BM;
    const int bn = by * 256;
    const long long z = bz;

    const ushort* AHb = AH + z * sA;
    const ushort* ALb = SPLIT3 ? (AL + z * sA) : AHb;
    const ushort* BHb = BH + z * sB;
    const ushort* BLb = SPLIT3 ? (BL + z * sB) : BHb;

    const int t    = threadIdx.x;
    const int lane = t & 63;
    const int w    = t >> 6;
    const int wr   = w >> 2;        // 0..1
    const int wc   = w & 3;         // 0..3
    const int lrow = lane & 15;
    const int kg16 = (lane >> 4) * 16;

    const ushort* Ap; const ushort* Bp; int kc;
#define SELPLANES(tt_)                                                        \
    do {                                                                      \
        if constexpr (SPLIT3) {                                               \
            Ap = ((tt_) < 24) ? AHb : ALb;                                    \
            Bp = (((tt_) < 12) || ((tt_) >= 24)) ? BHb : BLb;                 \
            int seg_ = ((tt_) < 12) ? (tt_) : (((tt_) < 24) ? (tt_) - 12      \
                                                            : (tt_) - 24);   \
            kc = seg_ * 64;                                                   \
        } else { Ap = AHb; Bp = BHb; kc = (tt_) * 64; }                       \
    } while (0)

    // ---- prologue: stage tiles 0 and 1 ----
    SELPLANES(0);
    stage_plane<BM, KS>(Ap + kc, smem, t, bm, M - 1);
    stage_plane<256, KS>(Bp + kc, smem + 2 * ABYTES, t, bn, N - 1);
    SELPLANES(1);
    stage_plane<BM, KS>(Ap + kc, smem + ABYTES, t, bm, M - 1);
    stage_plane<256, KS>(Bp + kc, smem + 2 * ABYTES + 32768, t, bn, N - 1);
    if constexpr (VMN == 8) asm volatile("s_waitcnt vmcnt(8)" ::: "memory");
    else                    asm volatile("s_waitcnt vmcnt(6)" ::: "memory");
    __builtin_amdgcn_s_barrier();

    f32x4 acc[MREP][4] = {};

    for (int tt = 0; tt < NT; ++tt) {
        const int cur = tt & 1;
        char* Ab = smem + cur * ABYTES;
        char* Bb = smem + 2 * ABYTES + cur * 32768;

        __builtin_amdgcn_s_setprio(1);
        short8 bf[4][2];
        #pragma unroll
        for (int n = 0; n < 4; ++n)
            #pragma unroll
            for (int ks = 0; ks < 2; ++ks)
                bf[n][ks] = *(const short8*)(Bb + swz(wc * 64 + n * 16 + lrow,
                                                      ks * 64 + kg16));
        #pragma unroll
        for (int q = 0; q < MREP / 2; ++q) {
            short8 af[2][2];
            #pragma unroll
            for (int mi = 0; mi < 2; ++mi)
                #pragma unroll
                for (int ks = 0; ks < 2; ++ks)
                    af[mi][ks] = *(const short8*)(Ab +
                        swz(wr * (BM / 2) + (q * 2 + mi) * 16 + lrow,
                            ks * 64 + kg16));
            #pragma unroll
            for (int ks = 0; ks < 2; ++ks)
                #pragma unroll
                for (int mi = 0; mi < 2; ++mi)
                    #pragma unroll
                    for (int n = 0; n < 4; ++n)
                        acc[q * 2 + mi][n] = __builtin_amdgcn_mfma_f32_16x16x32_bf16(
                            af[mi][ks], bf[n][ks], acc[q * 2 + mi][n], 0, 0, 0);
        }
        __builtin_amdgcn_s_setprio(0);

        asm volatile("s_waitcnt lgkmcnt(0)" ::: "memory");
        __builtin_amdgcn_s_barrier();

        if (tt + 2 < NT) {
            SELPLANES(tt + 2);
            stage_plane<BM, KS>(Ap + kc, smem + cur * ABYTES, t, bm, M - 1);
            stage_plane<256, KS>(Bp + kc, smem + 2 * ABYTES + cur * 32768,
                                 t, bn, N - 1);
            if constexpr (VMN == 8)
                asm volatile("s_waitcnt vmcnt(8)" ::: "memory");
            else
                asm volatile("s_waitcnt vmcnt(6)" ::: "memory");
        } else {
            asm volatile("s_waitcnt vmcnt(0)" ::: "memory");
        }
        __builtin_amdgcn_s_barrier();
    }
#undef SELPLANES

    // ---- epilogue: C write ----
    float* C = Cb + z * sC;
    const int r0 = bm + wr * (BM / 2) + (lane >> 4) * 4;
    const int c0 = bn + wc * 64 + (lane & 15);
    #pragma unroll
    for (int n = 0; n < 4; ++n) {
        const int col = c0 + n * 16;
        #pragma unroll
        for (int mi = 0; mi < MREP; ++mi) {
            #pragma unroll
            for (int r = 0; r < 4; ++r) {
                const int row = r0 + mi * 16 + r;
                if (row < M) C[(long long)row * N + col] = acc[mi][n][r];
            }
        }
    }

    if constexpr (STATS) {
        // fused per-column (max, sum) over this block's BM rows, chunk = bx
        __syncthreads();
        float* red = (float*)smem;                       // [256][8]
        const int slot = wr * 4 + (lane >> 4);
        const int colb = wc * 64 + (lane & 15);

        float lm[4];
        #pragma unroll
        for (int n = 0; n < 4; ++n) {
            float v = -INFINITY;
            #pragma unroll
            for (int mi = 0; mi < MREP; ++mi)
                #pragma unroll
                for (int r = 0; r < 4; ++r)
                    if (r0 + mi * 16 + r < M) v = fmaxf(v, acc[mi][n][r]);
            lm[n] = v;
        }
        #pragma unroll
        for (int n = 0; n < 4; ++n)
            red[(colb + n * 16) * 8 + slot] = lm[n];
        __syncthreads();
        float cm[4];
        #pragma unroll
        for (int n = 0; n < 4; ++n) {
            float v = -INFINITY;
            #pragma unroll
            for (int s8 = 0; s8 < 8; ++s8)
                v = fmaxf(v, red[(colb + n * 16) * 8 + s8]);
            cm[n] = v;
        }
        __syncthreads();
        float ls[4];
        #pragma unroll
        for (int n = 0; n < 4; ++n) {
            float sum = 0.f;
            #pragma unroll
            for (int mi = 0; mi < MREP; ++mi)
                #pragma unroll
                for (int r = 0; r < 4; ++r)
                    if (r0 + mi * 16 + r < M) sum += __expf(acc[mi][n][r] - cm[n]);
            ls[n] = sum;
        }
        #pragma unroll
        for (int n = 0; n < 4; ++n)
            red[(colb + n * 16) * 8 + slot] = ls[n];
        __syncthreads();
        if (slot == 0) {
            #pragma unroll
            for (int n = 0; n < 4; ++n) {
                float sum = 0.f;
                #pragma unroll
                for (int s8 = 0; s8 < 8; ++s8)
                    sum += red[(colb + n * 16) * 8 + s8];
                const int col = bn + colb + n * 16;
                pmo[(z * SM_CH + bx) * N + col] = cm[n];
                pso[(z * SM_CH + bx) * N + col] = sum;
            }
        }
    }
}

// ---------------------------------------------------------------------------
// split f32 array -> hi/lo bf16 planes (one-shot, for label)
// ---------------------------------------------------------------------------
__global__ __launch_bounds__(256) void split_planes_kernel(
    const float* __restrict__ in, ushort* __restrict__ H,
    ushort* __restrict__ L, long long n4)
{
    long long i = (long long)blockIdx.x * 256 + threadIdx.x;
    if (i >= n4) return;
    float4 v = *(const float4*)(in + i * 4);
    ushort h[4], l[4];
    split2(v.x, h[0], l[0]); split2(v.y, h[1], l[1]);
    split2(v.z, h[2], l[2]); split2(v.w, h[3], l[3]);
    *(ushort4*)(H + i * 4) = *(ushort4*)h;
    *(ushort4*)(L + i * 4) = *(ushort4*)l;
}

// ---------------------------------------------------------------------------
// proj GEMM (R6, unchanged): projH/projL = split2(tanh(lhs @ W^T + bias))
// ---------------------------------------------------------------------------
__global__ __launch_bounds__(256) void mfma_proj(
    const float* __restrict__ Ab, const float* __restrict__ Bb,
    ushort* __restrict__ CH, ushort* __restrict__ CL,
    const float* __restrict__ bias, int M, int N, int K)
{
    extern __shared__ char smem[];
    char* Ah = smem;
    char* Al = smem + 16384;
    char* Bh = smem + 32768;
    char* Bl = smem + 49152;

    int bx, by, bz; xcd_remap(bx, by, bz);
    const int bm = bx * 128;
    const int bn = by * 128;

    const int t  = threadIdx.x;
    const int srow = t >> 1;
    const int skh  = (t & 1) * 32;
    const float* ap = Ab + (long long)min(bm + srow, M - 1) * K + skh;
    const float* bp = Bb + (long long)min(bn + srow, N - 1) * K + skh;

    const int lane = t & 63;
    const int w    = t >> 6;
    const int wm   = (w >> 1) * 64;
    const int wn   = (w & 1) * 64;
    const int lrow = lane & 15;
    const int kg16 = (lane >> 4) * 16;

    f32x4 acc[4][4] = {};

    for (int k0 = 0; k0 < K; k0 += 64) {
        #pragma unroll
        for (int j = 0; j < 4; ++j) {
            float xs[8];
            *(float4*)&xs[0] = *(const float4*)(ap + k0 + j * 8);
            *(float4*)&xs[4] = *(const float4*)(ap + k0 + j * 8 + 4);
            ushort oh[8], ol[8];
            #pragma unroll
            for (int i = 0; i < 8; ++i) split2(xs[i], oh[i], ol[i]);
            const int off = swz(srow, skh * 2 + j * 16);
            *(uint4*)(Ah + off) = *(uint4*)oh;
            *(uint4*)(Al + off) = *(uint4*)ol;
        }
        #pragma unroll
        for (int j = 0; j < 4; ++j) {
            float xs[8];
            *(float4*)&xs[0] = *(const float4*)(bp + k0 + j * 8);
            *(float4*)&xs[4] = *(const float4*)(bp + k0 + j * 8 + 4);
            ushort oh[8], ol[8];
            #pragma unroll
            for (int i = 0; i < 8; ++i) split2(xs[i], oh[i], ol[i]);
            const int off = swz(srow, skh * 2 + j * 16);
            *(uint4*)(Bh + off) = *(uint4*)oh;
            *(uint4*)(Bl + off) = *(uint4*)ol;
        }
        __syncthreads();

        #pragma unroll
        for (int kk = 0; kk < 2; ++kk) {
            short8 ah[4], al[4];
            #pragma unroll
            for (int mi = 0; mi < 4; ++mi) {
                const int off = swz(wm + mi * 16 + lrow, kk * 64 + kg16);
                ah[mi] = *(const short8*)(Ah + off);
                al[mi] = *(const short8*)(Al + off);
            }
            #pragma unroll
            for (int ni = 0; ni < 4; ++ni) {
                const int off = swz(wn + ni * 16 + lrow, kk * 64 + kg16);
                short8 bh = *(const short8*)(Bh + off);
                short8 bl = *(const short8*)(Bl + off);
                #pragma unroll
                for (int mi = 0; mi < 4; ++mi) {
                    acc[mi][ni] = __builtin_amdgcn_mfma_f32_16x16x32_bf16(al[mi], bh, acc[mi][ni], 0, 0, 0);
                    acc[mi][ni] = __builtin_amdgcn_mfma_f32_16x16x32_bf16(ah[mi], bl, acc[mi][ni], 0, 0, 0);
                    acc[mi][ni] = __builtin_amdgcn_mfma_f32_16x16x32_bf16(ah[mi], bh, acc[mi][ni], 0, 0, 0);
                }
            }
        }
        __syncthreads();
    }

    const int r0 = bm + wm + (lane >> 4) * 4;
    const int c0 = bn + wn + (lane & 15);
    #pragma unroll
    for (int ni = 0; ni < 4; ++ni) {
        const int col = c0 + ni * 16;
        const float bv = bias[col];
        #pragma unroll
        for (int mi = 0; mi < 4; ++mi) {
            #pragma unroll
            for (int r = 0; r < 4; ++r) {
                const int row = r0 + mi * 16 + r;
                if (row < M) {
                    float x = tanhf(acc[mi][ni][r] + bv);
                    ushort h, l;
                    split2(x, h, l);
                    CH[(long long)row * N + col] = h;
                    CL[(long long)row * N + col] = l;
                }
            }
        }
    }
}

// ---------------------------------------------------------------------------
// lhs [B,S,D] f32  ->  lhsT [B,D,S] bf16
// ---------------------------------------------------------------------------
__global__ __launch_bounds__(256) void transpose_bf16_kernel(
    const float* __restrict__ in, ushort* __restrict__ out, int S, int D)
{
    __shared__ float tile[32][33];
    const int b = blockIdx.z;
    const int s0 = blockIdx.x * 32, d0 = blockIdx.y * 32;
    const int tx = threadIdx.x & 31, ty = threadIdx.x >> 5;
    const float* ip = in + (long long)b * S * D;
    #pragma unroll
    for (int i = 0; i < 32; i += 8)
        tile[ty + i][tx] = ip[(long long)(s0 + ty + i) * D + d0 + tx];
    __syncthreads();
    ushort* op = out + (long long)b * S * D;
    #pragma unroll
    for (int i = 0; i < 32; i += 8)
        op[(long long)(d0 + ty + i) * S + s0 + tx] = f2bf(tile[tx][ty + i]);
}

// ---------------------------------------------------------------------------
// Softmax merge + write (chunk stats from scores epilogue, SM_CH chunks).
// ---------------------------------------------------------------------------
__global__ __launch_bounds__(256) void softmax_merge_kernel(
    const float* __restrict__ pm, const float* __restrict__ ps,
    float* __restrict__ fm, float* __restrict__ fsinv, int S)
{
    int s = blockIdx.x * 256 + threadIdx.x;
    int b = blockIdx.y;
    float m = -INFINITY;
    #pragma unroll
    for (int c = 0; c < SM_CH; ++c)
        m = fmaxf(m, pm[(b * SM_CH + c) * S + s]);
    float sum = 0.f;
    #pragma unroll
    for (int c = 0; c < SM_CH; ++c)
        sum += ps[(b * SM_CH + c) * S + s] * __expf(pm[(b * SM_CH + c) * S + s] - m);
    fm[b * S + s] = m;
    fsinv[b * S + s] = 1.f / sum;
}

__global__ __launch_bounds__(256) void softmax_write_kernel(
    float* __restrict__ scores, const float* __restrict__ fm,
    const float* __restrict__ fsinv, int L, int S, int chlen,
    ushort* __restrict__ wbf)
{
    int s = blockIdx.x * 256 + threadIdx.x;
    int c = blockIdx.y;
    int b = blockIdx.z;
    float m   = fm[b * S + s];
    float inv = fsinv[b * S + s];
    float* p = scores + (long long)b * L * S + s;
    ushort* q = wbf + (long long)b * L * S + s;
    int l0 = c * chlen;
    int l1 = min(L, l0 + chlen);
    for (int l = l0; l < l1; ++l) {
        float x = p[(long long)l * S];
        float v = __expf(x - m) * inv;
        p[(long long)l * S] = v;
        q[(long long)l * S] = f2bf(v);
    }
}

extern "C" void kernel_launch(void* const* d_in, const int* in_sizes, int n_in,
                              void* d_out, int out_size, void* d_ws, size_t ws_size,
                              hipStream_t stream)
{
    const int Bn = 8, S = 512, D = 768, E = 768, L = 4000;
    const float* lhs   = (const float*)d_in[0];   // [B,S,D]
    const float* label = (const float*)d_in[1];   // [L,E]
    const float* W     = (const float*)d_in[2];   // [E,D]
    const float* bias  = (const float*)d_in[3];   // [E]

    float* weights = (float*)d_out;                          // [B,L,S]
    float* attn    = (float*)d_out + (long long)Bn * L * S;  // [B,L,D]

    const long long nLE  = (long long)L * E;        // 3,072,000
    const long long nBSE = (long long)Bn * S * E;   // 3,145,728
    const long long nBDS = (long long)Bn * D * S;   // 3,145,728
    const long long nBLS = (long long)Bn * L * S;   // 16,384,000

    ushort* labelH = (ushort*)d_ws;
    ushort* labelL = labelH + nLE;
    ushort* projH  = labelL + nLE;
    ushort* projL  = projH + nBSE;
    ushort* lhsT   = projL + nBSE;
    ushort* wbf    = lhsT + nBDS;
    float*  pm     = (float*)(wbf + nBLS);
    float*  ps     = pm + Bn * SM_CH * S;
    float*  fm     = ps + Bn * SM_CH * S;
    float*  fsinv  = fm + Bn * S;

    // scores: SPLIT3, BM=256, MREP=8, STATS, NT=36 (K=3*768), KS=768, VMN=8
    auto scoresK = mfma8<true, 256, 8, true, 36, 768, 8>;
    // attn: plain, BM=128, MREP=4, NT=8 (K=512), KS=512, VMN=6
    auto attnK   = mfma8<false, 128, 4, false, 8, 512, 6>;
    hipFuncSetAttribute((const void*)scoresK,
                        hipFuncAttributeMaxDynamicSharedMemorySize, 131072);
    hipFuncSetAttribute((const void*)attnK,
                        hipFuncAttributeMaxDynamicSharedMemorySize, 98304);

    // 0) lhsT (bf16 transpose) + label hi/lo planes
    transpose_bf16_kernel<<<dim3(S / 32, D / 32, Bn), 256, 0, stream>>>(
        lhs, lhsT, S, D);
    split_planes_kernel<<<(int)(nLE / 4 + 255) / 256, 256, 0, stream>>>(
        label, labelH, labelL, nLE / 4);

    // 1) projH/L = split(tanh(lhs @ W^T + bias))
    mfma_proj<<<dim3((Bn * S) / 128, E / 128, 1), 256, 65536, stream>>>(
        lhs, W, projH, projL, bias, Bn * S, E, D);

    // 2) scores + fused per-chunk (max,sum): M=L, N=S, pseudo-K=2304
    scoresK<<<dim3((L + 255) / 256, S / 256, Bn), 512, 131072, stream>>>(
        labelH, labelL, projH, projL, weights, pm, ps,
        L, S, 0LL, (long long)S * E, (long long)L * S);

    // 3) softmax merge + write (in place, + bf16 copy)
    softmax_merge_kernel<<<dim3(S / 256, Bn), 256, 0, stream>>>(
        pm, ps, fm, fsinv, S);
    softmax_write_kernel<<<dim3(S / 256, WCH, Bn), 256, 0, stream>>>(
        weights, fm, fsinv, L, S, (L + WCH - 1) / WCH, wbf);

    // 4) attn = wbf @ lhsT^T: M=L, N=D, K=512  (A batched by L*S!)
    attnK<<<dim3((L + 127) / 128, D / 256, Bn), 512, 98304, stream>>>(
        wbf, nullptr, lhsT, nullptr, attn, nullptr, nullptr,
        L, D, (long long)L * S, (long long)D * S, (long long)L * D);
}

// Round 9
// 243.921 us; speedup vs baseline: 3.5712x; 1.0282x over previous
//
#include <hip/hip_runtime.h>
#include <hip/hip_bf16.h>
#include <cmath>

typedef __attribute__((ext_vector_type(8))) short short8;
typedef __attribute__((ext_vector_type(4))) float f32x4;

#define SM_CH 16   // scores stats chunks: 4000 rows / 256-row blocks -> 16
#define WCH   32   // softmax write-pass chunking

__device__ inline ushort f2bf(float x) {
    union { float f; unsigned u; } v; v.f = x;
    unsigned r = v.u + 0x7FFF + ((v.u >> 16) & 1);   // RNE
    return (ushort)(r >> 16);
}

__device__ inline void split2(float x, ushort& hi, ushort& lo) {
    union { float f; unsigned u; } v; v.f = x;
    hi = (ushort)(v.u >> 16);
    union { float f; unsigned u; } h; h.u = v.u & 0xFFFF0000u;
    union { float f; unsigned u; } d; d.f = x - h.f;
    lo = (ushort)(d.u >> 16);
}

// byte offset within one [rows x 128B] LDS plane, XOR-swizzled (T2).
__device__ inline int swz(int row, int byte_in_row) {
    return row * 128 + (byte_in_row ^ ((row & 7) << 4));
}

// async global->LDS, 16B/lane; lds base wave-uniform, HW adds lane*16.
__device__ inline void gload16(const void* g, void* lds) {
    __builtin_amdgcn_global_load_lds(
        (const __attribute__((address_space(1))) unsigned int*)g,
        (__attribute__((address_space(3))) unsigned int*)lds, 16, 0, 0);
}

// T1: bijective XCD-aware block remap (requires nwg % 8 == 0).
__device__ inline void xcd_remap(int& bx, int& by, int& bz) {
    unsigned nx = gridDim.x, ny = gridDim.y;
    unsigned nwg = nx * ny * gridDim.z;
    unsigned id = blockIdx.x + nx * (blockIdx.y + ny * blockIdx.z);
    unsigned q = nwg >> 3;
    unsigned s = (id & 7) * q + (id >> 3);
    bx = s % nx; unsigned r = s / nx;
    by = r % ny; bz = r / ny;
}

// ---------------------------------------------------------------------------
// scores GEMM v2: weights[b] = labelHL @ projHL[b]^T, 3-term split.
// BK=32, paired-plane LDS rows: [hi 32k | lo 32k] = 128B. All 4 planes
// staged ONCE per K-tile (64KB, dbuf in 128KB LDS); 24 ds_read feed 96 MFMA.
// Fused per-column (max,sum) partials over the block's 256 rows.
// ---------------------------------------------------------------------------
__global__ __launch_bounds__(512, 2) void mfma_sc2(
    const ushort* __restrict__ AH, const ushort* __restrict__ AL,
    const ushort* __restrict__ BH, const ushort* __restrict__ BL,
    float* __restrict__ Cb, float* __restrict__ pmo, float* __restrict__ pso,
    int M, int N, long long sB, long long sC)
{
    extern __shared__ char smem[];
    // layout: [A0 32K | A1 32K | B0 32K | B1 32K]
    const int K = 768;

    int bx, by, bz; xcd_remap(bx, by, bz);
    const int bm = bx * 256;
    const int bn = by * 256;
    const long long z = bz;

    const ushort* BHb = BH + z * sB;
    const ushort* BLb = BL + z * sB;

    const int t    = threadIdx.x;
    const int lane = t & 63;
    const int w    = t >> 6;
    const int wr   = w >> 2;        // 0..1
    const int wc   = w & 3;         // 0..3
    const int lrow = lane & 15;
    const int kg16 = (lane >> 4) * 16;

    // staging: 4 A-chunks + 4 B-chunks per thread. Physical slot p=lane&7 of
    // row holds logical slot q = p ^ (row&7); q<4 -> hi plane, else lo plane.
    const ushort* srcA[4]; const ushort* srcB[4]; int ldsO[4];
    #pragma unroll
    for (int i = 0; i < 4; ++i) {
        const int row  = w * 32 + i * 8 + (lane >> 3);
        const int q    = (lane & 7) ^ (row & 7);
        const int colo = (q & 3) * 8;
        srcA[i] = ((q < 4) ? AH : AL) + (long long)min(bm + row, M - 1) * K + colo;
        srcB[i] = ((q < 4) ? BHb : BLb) + (long long)(bn + row) * K + colo;
        ldsO[i] = w * 4096 + i * 1024;  // wave-uniform
    }

#define STAGE(k0_, cur_)                                                      \
    {                                                                         \
        _Pragma("unroll")                                                     \
        for (int i = 0; i < 4; ++i) {                                         \
            gload16(srcA[i] + (k0_), smem + (cur_) * 32768 + ldsO[i]);        \
            gload16(srcB[i] + (k0_), smem + 65536 + (cur_) * 32768 + ldsO[i]);\
        }                                                                     \
    }

    // prologue: tiles 0 and 1
    STAGE(0, 0);
    STAGE(32, 1);
    asm volatile("s_waitcnt vmcnt(8)" ::: "memory");
    __builtin_amdgcn_s_barrier();

    f32x4 acc[8][4] = {};

    for (int tt = 0; tt < 24; ++tt) {
        const int cur = tt & 1;
        const char* Ab = smem + cur * 32768;
        const char* Bb = smem + 65536 + cur * 32768;

        __builtin_amdgcn_s_setprio(1);
        short8 bh[4], bl[4];
        #pragma unroll
        for (int n = 0; n < 4; ++n) {
            bh[n] = *(const short8*)(Bb + swz(wc * 64 + n * 16 + lrow, kg16));
            bl[n] = *(const short8*)(Bb + swz(wc * 64 + n * 16 + lrow, 64 + kg16));
        }
        #pragma unroll
        for (int g = 0; g < 2; ++g) {
            short8 ah[4], al[4];
            #pragma unroll
            for (int m4 = 0; m4 < 4; ++m4) {
                const int r = wr * 128 + (g * 4 + m4) * 16 + lrow;
                ah[m4] = *(const short8*)(Ab + swz(r, kg16));
                al[m4] = *(const short8*)(Ab + swz(r, 64 + kg16));
            }
            #pragma unroll
            for (int m4 = 0; m4 < 4; ++m4)
                #pragma unroll
                for (int n = 0; n < 4; ++n) {
                    acc[g*4+m4][n] = __builtin_amdgcn_mfma_f32_16x16x32_bf16(
                        al[m4], bh[n], acc[g*4+m4][n], 0, 0, 0);
                    acc[g*4+m4][n] = __builtin_amdgcn_mfma_f32_16x16x32_bf16(
                        ah[m4], bl[n], acc[g*4+m4][n], 0, 0, 0);
                    acc[g*4+m4][n] = __builtin_amdgcn_mfma_f32_16x16x32_bf16(
                        ah[m4], bh[n], acc[g*4+m4][n], 0, 0, 0);
                }
        }
        __builtin_amdgcn_s_setprio(0);

        asm volatile("s_waitcnt lgkmcnt(0)" ::: "memory");
        __builtin_amdgcn_s_barrier();

        if (tt + 2 < 24) {
            STAGE((tt + 2) * 32, cur);
            asm volatile("s_waitcnt vmcnt(8)" ::: "memory");
        } else {
            asm volatile("s_waitcnt vmcnt(0)" ::: "memory");
        }
        __builtin_amdgcn_s_barrier();
    }
#undef STAGE

    // ---- C write ----
    float* C = Cb + z * sC;
    const int r0 = bm + wr * 128 + (lane >> 4) * 4;
    const int c0 = bn + wc * 64 + (lane & 15);
    #pragma unroll
    for (int n = 0; n < 4; ++n) {
        const int col = c0 + n * 16;
        #pragma unroll
        for (int mi = 0; mi < 8; ++mi) {
            #pragma unroll
            for (int r = 0; r < 4; ++r) {
                const int row = r0 + mi * 16 + r;
                if (row < M) C[(long long)row * N + col] = acc[mi][n][r];
            }
        }
    }

    // ---- fused per-column (max, sum) over the block's 256 rows ----
    __syncthreads();
    float* red = (float*)smem;                       // [256][8]
    const int slot = wr * 4 + (lane >> 4);
    const int colb = wc * 64 + (lane & 15);

    float lm[4];
    #pragma unroll
    for (int n = 0; n < 4; ++n) {
        float v = -INFINITY;
        #pragma unroll
        for (int mi = 0; mi < 8; ++mi)
            #pragma unroll
            for (int r = 0; r < 4; ++r)
                if (r0 + mi * 16 + r < M) v = fmaxf(v, acc[mi][n][r]);
        lm[n] = v;
    }
    #pragma unroll
    for (int n = 0; n < 4; ++n)
        red[(colb + n * 16) * 8 + slot] = lm[n];
    __syncthreads();
    float cm[4];
    #pragma unroll
    for (int n = 0; n < 4; ++n) {
        float v = -INFINITY;
        #pragma unroll
        for (int s8 = 0; s8 < 8; ++s8)
            v = fmaxf(v, red[(colb + n * 16) * 8 + s8]);
        cm[n] = v;
    }
    __syncthreads();
    float ls[4];
    #pragma unroll
    for (int n = 0; n < 4; ++n) {
        float sum = 0.f;
        #pragma unroll
        for (int mi = 0; mi < 8; ++mi)
            #pragma unroll
            for (int r = 0; r < 4; ++r)
                if (r0 + mi * 16 + r < M) sum += __expf(acc[mi][n][r] - cm[n]);
        ls[n] = sum;
    }
    #pragma unroll
    for (int n = 0; n < 4; ++n)
        red[(colb + n * 16) * 8 + slot] = ls[n];
    __syncthreads();
    if (slot == 0) {
        #pragma unroll
        for (int n = 0; n < 4; ++n) {
            float sum = 0.f;
            #pragma unroll
            for (int s8 = 0; s8 < 8; ++s8)
                sum += red[(colb + n * 16) * 8 + s8];
            const int col = bn + colb + n * 16;
            pmo[(z * SM_CH + bx) * N + col] = cm[n];
            pso[(z * SM_CH + bx) * N + col] = sum;
        }
    }
}

// ---------------------------------------------------------------------------
// attn GEMM (R8-proven): 8-wave, BM=128 x BN=256, BK=64, dbuf, counted vmcnt.
// ---------------------------------------------------------------------------
template<int ROWS, int KS>
__device__ inline void stage_plane(const ushort* __restrict__ src,
                                   char* plane, int t, int rbase, int rmax)
{
    #pragma unroll
    for (int s = 0; s < ROWS / 64; ++s) {
        const int row = s * 64 + (t >> 3);
        const int col = (((t & 7) * 16) ^ ((row & 7) << 4)) >> 1;  // elems
        const int gr  = min(rbase + row, rmax);
        gload16(src + (long long)gr * KS + col,
                plane + s * 8192 + (t >> 6) * 1024);
    }
}

__global__ __launch_bounds__(512, 2) void mfma_attn8(
    const ushort* __restrict__ A, const ushort* __restrict__ B,
    float* __restrict__ Cb, int M, int N,
    long long sA, long long sB, long long sC)
{
    extern __shared__ char smem[];
    constexpr int ABYTES = 128 * 128;   // one A buffer (BM=128)
    constexpr int NT = 8, KS = 512;

    int bx, by, bz; xcd_remap(bx, by, bz);
    const int bm = bx * 128;
    const int bn = by * 256;
    const long long z = bz;

    const ushort* Ab_g = A + z * sA;
    const ushort* Bb_g = B + z * sB;

    const int t    = threadIdx.x;
    const int lane = t & 63;
    const int w    = t >> 6;
    const int wr   = w >> 2;
    const int wc   = w & 3;
    const int lrow = lane & 15;
    const int kg16 = (lane >> 4) * 16;

    stage_plane<128, KS>(Ab_g, smem, t, bm, M - 1);
    stage_plane<256, KS>(Bb_g, smem + 2 * ABYTES, t, bn, N - 1);
    stage_plane<128, KS>(Ab_g + 64, smem + ABYTES, t, bm, M - 1);
    stage_plane<256, KS>(Bb_g + 64, smem + 2 * ABYTES + 32768, t, bn, N - 1);
    asm volatile("s_waitcnt vmcnt(6)" ::: "memory");
    __builtin_amdgcn_s_barrier();

    f32x4 acc[4][4] = {};

    for (int tt = 0; tt < NT; ++tt) {
        const int cur = tt & 1;
        char* Ab = smem + cur * ABYTES;
        char* Bb = smem + 2 * ABYTES + cur * 32768;

        __builtin_amdgcn_s_setprio(1);
        short8 bf[4][2];
        #pragma unroll
        for (int n = 0; n < 4; ++n)
            #pragma unroll
            for (int ks = 0; ks < 2; ++ks)
                bf[n][ks] = *(const short8*)(Bb + swz(wc * 64 + n * 16 + lrow,
                                                      ks * 64 + kg16));
        #pragma unroll
        for (int q = 0; q < 2; ++q) {
            short8 af[2][2];
            #pragma unroll
            for (int mi = 0; mi < 2; ++mi)
                #pragma unroll
                for (int ks = 0; ks < 2; ++ks)
                    af[mi][ks] = *(const short8*)(Ab +
                        swz(wr * 64 + (q * 2 + mi) * 16 + lrow, ks * 64 + kg16));
            #pragma unroll
            for (int ks = 0; ks < 2; ++ks)
                #pragma unroll
                for (int mi = 0; mi < 2; ++mi)
                    #pragma unroll
                    for (int n = 0; n < 4; ++n)
                        acc[q * 2 + mi][n] = __builtin_amdgcn_mfma_f32_16x16x32_bf16(
                            af[mi][ks], bf[n][ks], acc[q * 2 + mi][n], 0, 0, 0);
        }
        __builtin_amdgcn_s_setprio(0);

        asm volatile("s_waitcnt lgkmcnt(0)" ::: "memory");
        __builtin_amdgcn_s_barrier();

        if (tt + 2 < NT) {
            stage_plane<128, KS>(Ab_g + (tt + 2) * 64, smem + cur * ABYTES,
                                 t, bm, M - 1);
            stage_plane<256, KS>(Bb_g + (tt + 2) * 64,
                                 smem + 2 * ABYTES + cur * 32768, t, bn, N - 1);
            asm volatile("s_waitcnt vmcnt(6)" ::: "memory");
        } else {
            asm volatile("s_waitcnt vmcnt(0)" ::: "memory");
        }
        __builtin_amdgcn_s_barrier();
    }

    float* C = Cb + z * sC;
    const int r0 = bm + wr * 64 + (lane >> 4) * 4;
    const int c0 = bn + wc * 64 + (lane & 15);
    #pragma unroll
    for (int n = 0; n < 4; ++n) {
        const int col = c0 + n * 16;
        #pragma unroll
        for (int mi = 0; mi < 4; ++mi) {
            #pragma unroll
            for (int r = 0; r < 4; ++r) {
                const int row = r0 + mi * 16 + r;
                if (row < M) C[(long long)row * N + col] = acc[mi][n][r];
            }
        }
    }
}

// ---------------------------------------------------------------------------
// split f32 array -> hi/lo bf16 planes (one-shot, for label)
// ---------------------------------------------------------------------------
__global__ __launch_bounds__(256) void split_planes_kernel(
    const float* __restrict__ in, ushort* __restrict__ H,
    ushort* __restrict__ L, long long n4)
{
    long long i = (long long)blockIdx.x * 256 + threadIdx.x;
    if (i >= n4) return;
    float4 v = *(const float4*)(in + i * 4);
    ushort h[4], l[4];
    split2(v.x, h[0], l[0]); split2(v.y, h[1], l[1]);
    split2(v.z, h[2], l[2]); split2(v.w, h[3], l[3]);
    *(ushort4*)(H + i * 4) = *(ushort4*)h;
    *(ushort4*)(L + i * 4) = *(ushort4*)l;
}

// ---------------------------------------------------------------------------
// proj GEMM (R6, unchanged): projH/projL = split2(tanh(lhs @ W^T + bias))
// ---------------------------------------------------------------------------
__global__ __launch_bounds__(256) void mfma_proj(
    const float* __restrict__ Ab, const float* __restrict__ Bb,
    ushort* __restrict__ CH, ushort* __restrict__ CL,
    const float* __restrict__ bias, int M, int N, int K)
{
    extern __shared__ char smem[];
    char* Ah = smem;
    char* Al = smem + 16384;
    char* Bh = smem + 32768;
    char* Bl = smem + 49152;

    int bx, by, bz; xcd_remap(bx, by, bz);
    const int bm = bx * 128;
    const int bn = by * 128;

    const int t  = threadIdx.x;
    const int srow = t >> 1;
    const int skh  = (t & 1) * 32;
    const float* ap = Ab + (long long)min(bm + srow, M - 1) * K + skh;
    const float* bp = Bb + (long long)min(bn + srow, N - 1) * K + skh;

    const int lane = t & 63;
    const int w    = t >> 6;
    const int wm   = (w >> 1) * 64;
    const int wn   = (w & 1) * 64;
    const int lrow = lane & 15;
    const int kg16 = (lane >> 4) * 16;

    f32x4 acc[4][4] = {};

    for (int k0 = 0; k0 < K; k0 += 64) {
        #pragma unroll
        for (int j = 0; j < 4; ++j) {
            float xs[8];
            *(float4*)&xs[0] = *(const float4*)(ap + k0 + j * 8);
            *(float4*)&xs[4] = *(const float4*)(ap + k0 + j * 8 + 4);
            ushort oh[8], ol[8];
            #pragma unroll
            for (int i = 0; i < 8; ++i) split2(xs[i], oh[i], ol[i]);
            const int off = swz(srow, skh * 2 + j * 16);
            *(uint4*)(Ah + off) = *(uint4*)oh;
            *(uint4*)(Al + off) = *(uint4*)ol;
        }
        #pragma unroll
        for (int j = 0; j < 4; ++j) {
            float xs[8];
            *(float4*)&xs[0] = *(const float4*)(bp + k0 + j * 8);
            *(float4*)&xs[4] = *(const float4*)(bp + k0 + j * 8 + 4);
            ushort oh[8], ol[8];
            #pragma unroll
            for (int i = 0; i < 8; ++i) split2(xs[i], oh[i], ol[i]);
            const int off = swz(srow, skh * 2 + j * 16);
            *(uint4*)(Bh + off) = *(uint4*)oh;
            *(uint4*)(Bl + off) = *(uint4*)ol;
        }
        __syncthreads();

        #pragma unroll
        for (int kk = 0; kk < 2; ++kk) {
            short8 ah[4], al[4];
            #pragma unroll
            for (int mi = 0; mi < 4; ++mi) {
                const int off = swz(wm + mi * 16 + lrow, kk * 64 + kg16);
                ah[mi] = *(const short8*)(Ah + off);
                al[mi] = *(const short8*)(Al + off);
            }
            #pragma unroll
            for (int ni = 0; ni < 4; ++ni) {
                const int off = swz(wn + ni * 16 + lrow, kk * 64 + kg16);
                short8 bh = *(const short8*)(Bh + off);
                short8 bl = *(const short8*)(Bl + off);
                #pragma unroll
                for (int mi = 0; mi < 4; ++mi) {
                    acc[mi][ni] = __builtin_amdgcn_mfma_f32_16x16x32_bf16(al[mi], bh, acc[mi][ni], 0, 0, 0);
                    acc[mi][ni] = __builtin_amdgcn_mfma_f32_16x16x32_bf16(ah[mi], bl, acc[mi][ni], 0, 0, 0);
                    acc[mi][ni] = __builtin_amdgcn_mfma_f32_16x16x32_bf16(ah[mi], bh, acc[mi][ni], 0, 0, 0);
                }
            }
        }
        __syncthreads();
    }

    const int r0 = bm + wm + (lane >> 4) * 4;
    const int c0 = bn + wn + (lane & 15);
    #pragma unroll
    for (int ni = 0; ni < 4; ++ni) {
        const int col = c0 + ni * 16;
        const float bv = bias[col];
        #pragma unroll
        for (int mi = 0; mi < 4; ++mi) {
            #pragma unroll
            for (int r = 0; r < 4; ++r) {
                const int row = r0 + mi * 16 + r;
                if (row < M) {
                    float x = tanhf(acc[mi][ni][r] + bv);
                    ushort h, l;
                    split2(x, h, l);
                    CH[(long long)row * N + col] = h;
                    CL[(long long)row * N + col] = l;
                }
            }
        }
    }
}

// ---------------------------------------------------------------------------
// lhs [B,S,D] f32  ->  lhsT [B,D,S] bf16
// ---------------------------------------------------------------------------
__global__ __launch_bounds__(256) void transpose_bf16_kernel(
    const float* __restrict__ in, ushort* __restrict__ out, int S, int D)
{
    __shared__ float tile[32][33];
    const int b = blockIdx.z;
    const int s0 = blockIdx.x * 32, d0 = blockIdx.y * 32;
    const int tx = threadIdx.x & 31, ty = threadIdx.x >> 5;
    const float* ip = in + (long long)b * S * D;
    #pragma unroll
    for (int i = 0; i < 32; i += 8)
        tile[ty + i][tx] = ip[(long long)(s0 + ty + i) * D + d0 + tx];
    __syncthreads();
    ushort* op = out + (long long)b * S * D;
    #pragma unroll
    for (int i = 0; i < 32; i += 8)
        op[(long long)(d0 + ty + i) * S + s0 + tx] = f2bf(tile[tx][ty + i]);
}

// ---------------------------------------------------------------------------
// Softmax write with inlined merge (reads chunk stats pm/ps directly).
// ---------------------------------------------------------------------------
__global__ __launch_bounds__(256) void softmax_write2_kernel(
    float* __restrict__ scores, const float* __restrict__ pm,
    const float* __restrict__ ps, int L, int S, int chlen,
    ushort* __restrict__ wbf)
{
    int s = blockIdx.x * 256 + threadIdx.x;
    int c = blockIdx.y;
    int b = blockIdx.z;

    float m = -INFINITY;
    #pragma unroll
    for (int k = 0; k < SM_CH; ++k)
        m = fmaxf(m, pm[(b * SM_CH + k) * S + s]);
    float sum = 0.f;
    #pragma unroll
    for (int k = 0; k < SM_CH; ++k)
        sum += ps[(b * SM_CH + k) * S + s] * __expf(pm[(b * SM_CH + k) * S + s] - m);
    float inv = 1.f / sum;

    float* p = scores + (long long)b * L * S + s;
    ushort* q = wbf + (long long)b * L * S + s;
    int l0 = c * chlen;
    int l1 = min(L, l0 + chlen);
    for (int l = l0; l < l1; ++l) {
        float x = p[(long long)l * S];
        float v = __expf(x - m) * inv;
        p[(long long)l * S] = v;
        q[(long long)l * S] = f2bf(v);
    }
}

extern "C" void kernel_launch(void* const* d_in, const int* in_sizes, int n_in,
                              void* d_out, int out_size, void* d_ws, size_t ws_size,
                              hipStream_t stream)
{
    const int Bn = 8, S = 512, D = 768, E = 768, L = 4000;
    const float* lhs   = (const float*)d_in[0];   // [B,S,D]
    const float* label = (const float*)d_in[1];   // [L,E]
    const float* W     = (const float*)d_in[2];   // [E,D]
    const float* bias  = (const float*)d_in[3];   // [E]

    float* weights = (float*)d_out;                          // [B,L,S]
    float* attn    = (float*)d_out + (long long)Bn * L * S;  // [B,L,D]

    const long long nLE  = (long long)L * E;        // 3,072,000
    const long long nBSE = (long long)Bn * S * E;   // 3,145,728
    const long long nBDS = (long long)Bn * D * S;   // 3,145,728
    const long long nBLS = (long long)Bn * L * S;   // 16,384,000

    ushort* labelH = (ushort*)d_ws;
    ushort* labelL = labelH + nLE;
    ushort* projH  = labelL + nLE;
    ushort* projL  = projH + nBSE;
    ushort* lhsT   = projL + nBSE;
    ushort* wbf    = lhsT + nBDS;
    float*  pm     = (float*)(wbf + nBLS);
    float*  ps     = pm + Bn * SM_CH * S;

    hipFuncSetAttribute((const void*)mfma_sc2,
                        hipFuncAttributeMaxDynamicSharedMemorySize, 131072);
    hipFuncSetAttribute((const void*)mfma_attn8,
                        hipFuncAttributeMaxDynamicSharedMemorySize, 98304);

    // 0) lhsT (bf16 transpose) + label hi/lo planes
    transpose_bf16_kernel<<<dim3(S / 32, D / 32, Bn), 256, 0, stream>>>(
        lhs, lhsT, S, D);
    split_planes_kernel<<<(int)(nLE / 4 + 255) / 256, 256, 0, stream>>>(
        label, labelH, labelL, nLE / 4);

    // 1) projH/L = split(tanh(lhs @ W^T + bias))
    mfma_proj<<<dim3((Bn * S) / 128, E / 128, 1), 256, 65536, stream>>>(
        lhs, W, projH, projL, bias, Bn * S, E, D);

    // 2) scores + fused per-chunk (max,sum): M=L, N=S, K=768, BK=32
    mfma_sc2<<<dim3((L + 255) / 256, S / 256, Bn), 512, 131072, stream>>>(
        labelH, labelL, projH, projL, weights, pm, ps,
        L, S, (long long)S * E, (long long)L * S);

    // 3) softmax write with inlined merge (in place, + bf16 copy)
    softmax_write2_kernel<<<dim3(S / 256, WCH, Bn), 256, 0, stream>>>(
        weights, pm, ps, L, S, (L + WCH - 1) / WCH, wbf);

    // 4) attn = wbf @ lhsT^T: M=L, N=D, K=512
    mfma_attn8<<<dim3((L + 127) / 128, D / 256, Bn), 512, 98304, stream>>>(
        wbf, lhsT, attn, L, D,
        (long long)L * S, (long long)D * S, (long long)L * D);
}